// Round 1
// baseline (4359.341 us; speedup 1.0000x reference)
//
#include <hip/hip_runtime.h>
#include <cmath>

// ---------- helpers ----------
__device__ __forceinline__ void fma4(float4& a, float s, const float4& b) {
    a.x = fmaf(s, b.x, a.x); a.y = fmaf(s, b.y, a.y);
    a.z = fmaf(s, b.z, a.z); a.w = fmaf(s, b.w, a.w);
}
__device__ __forceinline__ float getc(const float4& v, int i) {
    return i == 0 ? v.x : (i == 1 ? v.y : (i == 2 ? v.z : v.w));
}
__device__ __forceinline__ float dot4(const float4& a, const float4& b) {
    return a.x*b.x + a.y*b.y + a.z*b.z + a.w*b.w;
}
__device__ __forceinline__ float gelu_exact(float v) {
    return 0.5f * v * (1.0f + erff(v * 0.70710678118654752440f));
}

// ---------- K1: Q/K/V projection: feat(N,128) @ {Wq,Wk,Wv}(128,128) ----------
// tile: 32 nodes; block 384 threads; thread owns 4 cols x 8 rows.
__global__ __launch_bounds__(384, 1) void k_qkv(
    const float* __restrict__ feat,
    const float* __restrict__ Wq, const float* __restrict__ Wk, const float* __restrict__ Wv,
    float* __restrict__ Q, float* __restrict__ Kp, float* __restrict__ Vp, int n)
{
    __shared__ float ft[32][132];              // +4 pad: row-strided b128 reads hit distinct banks
    const int tid = threadIdx.x;
    const int row0 = blockIdx.x * 32;
    for (int i = tid; i < 1024; i += 384) {    // 32 rows x 32 float4
        int m = i >> 5, kk = i & 31;
        float4 v = make_float4(0.f, 0.f, 0.f, 0.f);
        int row = row0 + m;
        if (row < n) v = ((const float4*)(feat + (size_t)row * 128))[kk];
        *((float4*)&ft[m][kk * 4]) = v;
    }
    __syncthreads();

    const int ct = tid % 96;                   // 96 col-groups of 4 -> 384 cols
    const int g  = tid / 96;                   // 4 node-groups; rows = m*4+g
    const int c  = ct * 4;
    const float* W; float* O;
    if (c < 128)      { W = Wq; O = Q;  }
    else if (c < 256) { W = Wk; O = Kp; }
    else              { W = Wv; O = Vp; }
    const int cc = c & 127;

    float4 acc[8];
    #pragma unroll
    for (int m = 0; m < 8; ++m) acc[m] = make_float4(0.f, 0.f, 0.f, 0.f);

    for (int k4 = 0; k4 < 128; k4 += 4) {
        float4 f[8];
        #pragma unroll
        for (int m = 0; m < 8; ++m) f[m] = *((const float4*)&ft[m * 4 + g][k4]);
        #pragma unroll
        for (int kk = 0; kk < 4; ++kk) {
            float4 w = *((const float4*)(W + (size_t)(k4 + kk) * 128 + cc));
            #pragma unroll
            for (int m = 0; m < 8; ++m) fma4(acc[m], getc(f[m], kk), w);
        }
    }
    #pragma unroll
    for (int m = 0; m < 8; ++m) {
        int row = row0 + m * 4 + g;
        if (row < n) *((float4*)(O + (size_t)row * 128 + cc)) = acc[m];
    }
}

// ---------- K2: KNN attention -> attended(N,128). one wave per node ----------
__global__ __launch_bounds__(256, 1) void k_attn(
    const float* __restrict__ Q, const float* __restrict__ Kp, const float* __restrict__ Vp,
    const int* __restrict__ knn, const float* __restrict__ dist,
    float* __restrict__ att, int n)
{
    const int lane = threadIdx.x & 63;
    const int node = blockIdx.x * 4 + (threadIdx.x >> 6);
    if (node >= n) return;
    const int h = lane >> 3, r = lane & 7;     // 8 lanes per head; lane owns 4 neighbors

    const float* qp = Q + (size_t)node * 128 + h * 16;
    const float4 q0 = ((const float4*)qp)[0];
    const float4 q1 = ((const float4*)qp)[1];
    const float4 q2 = ((const float4*)qp)[2];
    const float4 q3 = ((const float4*)qp)[3];
    const float hs = exp2f(-(float)(h + 1));   // 0.5^(h+1)

    int idx[4]; float sd[4];
    #pragma unroll
    for (int jj = 0; jj < 4; ++jj) {
        int j = r + jj * 8;
        idx[jj] = knn[(size_t)node * 32 + j];
        sd[jj]  = dist[(size_t)node * 32 + j] * hs;
    }

    float ap[4], an[4];
    #pragma unroll
    for (int jj = 0; jj < 4; ++jj) {
        const float* kp = Kp + (size_t)idx[jj] * 128 + h * 16;
        float4 k0 = ((const float4*)kp)[0];
        float4 k1 = ((const float4*)kp)[1];
        float4 k2 = ((const float4*)kp)[2];
        float4 k3 = ((const float4*)kp)[3];
        float s = dot4(q0, k0) + dot4(q1, k1) + dot4(q2, k2) + dot4(q3, k3);
        float raw = s * 0.25f;                 // /sqrt(16)
        ap[jj] = raw - sd[jj];
        an[jj] = (-raw - sd[jj]) * (1.0f / 0.6f);
    }

    float mp = fmaxf(fmaxf(ap[0], ap[1]), fmaxf(ap[2], ap[3]));
    float mn = fmaxf(fmaxf(an[0], an[1]), fmaxf(an[2], an[3]));
    #pragma unroll
    for (int msk = 1; msk < 8; msk <<= 1) {
        mp = fmaxf(mp, __shfl_xor(mp, msk, 8));
        mn = fmaxf(mn, __shfl_xor(mn, msk, 8));
    }
    float ep[4], en[4], sp = 0.f, sn = 0.f;
    #pragma unroll
    for (int jj = 0; jj < 4; ++jj) {
        ep[jj] = expf(ap[jj] - mp); sp += ep[jj];
        en[jj] = expf(an[jj] - mn); sn += en[jj];
    }
    #pragma unroll
    for (int msk = 1; msk < 8; msk <<= 1) {
        sp += __shfl_xor(sp, msk, 8);
        sn += __shfl_xor(sn, msk, 8);
    }
    const float isp = 1.0f / sp;
    const float isn = 1.5f / sn;

    float4 a0 = make_float4(0,0,0,0), a1 = a0, a2 = a0, a3 = a0;
    #pragma unroll
    for (int jj = 0; jj < 4; ++jj) {
        float w = ep[jj] * isp - en[jj] * isn;
        const float* vp = Vp + (size_t)idx[jj] * 128 + h * 16;
        float4 v0 = ((const float4*)vp)[0];
        float4 v1 = ((const float4*)vp)[1];
        float4 v2 = ((const float4*)vp)[2];
        float4 v3 = ((const float4*)vp)[3];
        fma4(a0, w, v0); fma4(a1, w, v1); fma4(a2, w, v2); fma4(a3, w, v3);
    }
    #pragma unroll
    for (int msk = 1; msk < 8; msk <<= 1) {
        a0.x += __shfl_xor(a0.x, msk, 8); a0.y += __shfl_xor(a0.y, msk, 8);
        a0.z += __shfl_xor(a0.z, msk, 8); a0.w += __shfl_xor(a0.w, msk, 8);
        a1.x += __shfl_xor(a1.x, msk, 8); a1.y += __shfl_xor(a1.y, msk, 8);
        a1.z += __shfl_xor(a1.z, msk, 8); a1.w += __shfl_xor(a1.w, msk, 8);
        a2.x += __shfl_xor(a2.x, msk, 8); a2.y += __shfl_xor(a2.y, msk, 8);
        a2.z += __shfl_xor(a2.z, msk, 8); a2.w += __shfl_xor(a2.w, msk, 8);
        a3.x += __shfl_xor(a3.x, msk, 8); a3.y += __shfl_xor(a3.y, msk, 8);
        a3.z += __shfl_xor(a3.z, msk, 8); a3.w += __shfl_xor(a3.w, msk, 8);
    }
    if (r == 0) {
        float* op = att + (size_t)node * 128 + h * 16;
        ((float4*)op)[0] = a0; ((float4*)op)[1] = a1;
        ((float4*)op)[2] = a2; ((float4*)op)[3] = a3;
    }
}

// ---------- K3: x = LN1(attended @ Wo + bo + feat); written in-place over att ----------
__global__ __launch_bounds__(256, 1) void k_woln(
    const float* __restrict__ att, const float* __restrict__ Wo,
    const float* __restrict__ bo, const float* __restrict__ feat,
    const float* __restrict__ g1, const float* __restrict__ b1,
    float* __restrict__ X, int n)
{
    __shared__ float at[32][132];
    __shared__ float yt[32][132];
    const int tid = threadIdx.x;
    const int row0 = blockIdx.x * 32;
    for (int i = tid; i < 1024; i += 256) {
        int m = i >> 5, kk = i & 31;
        float4 v = make_float4(0.f, 0.f, 0.f, 0.f);
        int row = row0 + m;
        if (row < n) v = ((const float4*)(att + (size_t)row * 128))[kk];
        *((float4*)&at[m][kk * 4]) = v;
    }
    __syncthreads();

    const int ct = tid % 32, g = tid / 32;     // rows = m*8+g, m=0..3
    const int c = ct * 4;
    float4 acc[4];
    #pragma unroll
    for (int m = 0; m < 4; ++m) acc[m] = make_float4(0.f, 0.f, 0.f, 0.f);

    for (int k4 = 0; k4 < 128; k4 += 4) {
        float4 f[4];
        #pragma unroll
        for (int m = 0; m < 4; ++m) f[m] = *((const float4*)&at[m * 8 + g][k4]);
        #pragma unroll
        for (int kk = 0; kk < 4; ++kk) {
            float4 w = *((const float4*)(Wo + (size_t)(k4 + kk) * 128 + c));
            #pragma unroll
            for (int m = 0; m < 4; ++m) fma4(acc[m], getc(f[m], kk), w);
        }
    }
    const float4 bv = *((const float4*)(bo + c));
    #pragma unroll
    for (int m = 0; m < 4; ++m) {
        int row = row0 + m * 8 + g;
        float4 fr = make_float4(0.f, 0.f, 0.f, 0.f);
        if (row < n) fr = *((const float4*)(feat + (size_t)row * 128 + c));
        float4 y;
        y.x = acc[m].x + bv.x + fr.x; y.y = acc[m].y + bv.y + fr.y;
        y.z = acc[m].z + bv.z + fr.z; y.w = acc[m].w + bv.w + fr.w;
        *((float4*)&yt[m * 8 + g][c]) = y;
    }
    __syncthreads();

    // LayerNorm: 8 threads per node
    const int m = tid >> 3, rr = tid & 7;
    float s = 0.f;
    #pragma unroll
    for (int i = 0; i < 16; ++i) s += yt[m][i * 8 + rr];
    #pragma unroll
    for (int msk = 1; msk < 8; msk <<= 1) s += __shfl_xor(s, msk, 8);
    const float mu = s * (1.0f / 128.0f);
    float s2 = 0.f;
    #pragma unroll
    for (int i = 0; i < 16; ++i) { float d = yt[m][i * 8 + rr] - mu; s2 = fmaf(d, d, s2); }
    #pragma unroll
    for (int msk = 1; msk < 8; msk <<= 1) s2 += __shfl_xor(s2, msk, 8);
    const float rs = rsqrtf(s2 * (1.0f / 128.0f) + 1e-5f);
    const int row = row0 + m;
    if (row < n) {
        #pragma unroll
        for (int i = 0; i < 16; ++i) {
            int cc = i * 8 + rr;
            X[(size_t)row * 128 + cc] = (yt[m][cc] - mu) * rs * g1[cc] + b1[cc];
        }
    }
}

// ---------- K4: out = LN2(gelu(x@W1+b1)@W2 + b2 + x) ----------
// tile 24 nodes, block 384
__global__ __launch_bounds__(384, 1) void k_ffn(
    const float* __restrict__ X, const float* __restrict__ W1, const float* __restrict__ b1,
    const float* __restrict__ W2, const float* __restrict__ b2,
    const float* __restrict__ g2, const float* __restrict__ bl2,
    float* __restrict__ out, int n)
{
    __shared__ float xt[24][132];
    __shared__ float ht[24][196];
    __shared__ float yt[24][132];
    const int tid = threadIdx.x;
    const int row0 = blockIdx.x * 24;
    for (int i = tid; i < 768; i += 384) {     // 24 x 32 float4
        int m = i >> 5, kk = i & 31;
        float4 v = make_float4(0.f, 0.f, 0.f, 0.f);
        int row = row0 + m;
        if (row < n) v = ((const float4*)(X + (size_t)row * 128))[kk];
        *((float4*)&xt[m][kk * 4]) = v;
    }
    __syncthreads();

    // phase 1: h = gelu(x@W1 + b1); 48 col-groups x 8 node-groups (rows m*8+g, m=0..2)
    {
        const int ct = tid % 48, g = tid / 48;
        const int c = ct * 4;
        float4 acc[3];
        #pragma unroll
        for (int m = 0; m < 3; ++m) acc[m] = make_float4(0.f, 0.f, 0.f, 0.f);
        for (int k4 = 0; k4 < 128; k4 += 4) {
            float4 f[3];
            #pragma unroll
            for (int m = 0; m < 3; ++m) f[m] = *((const float4*)&xt[m * 8 + g][k4]);
            #pragma unroll
            for (int kk = 0; kk < 4; ++kk) {
                float4 w = *((const float4*)(W1 + (size_t)(k4 + kk) * 192 + c));
                #pragma unroll
                for (int m = 0; m < 3; ++m) fma4(acc[m], getc(f[m], kk), w);
            }
        }
        const float4 bv = *((const float4*)(b1 + c));
        #pragma unroll
        for (int m = 0; m < 3; ++m) {
            float4 hv;
            hv.x = gelu_exact(acc[m].x + bv.x);
            hv.y = gelu_exact(acc[m].y + bv.y);
            hv.z = gelu_exact(acc[m].z + bv.z);
            hv.w = gelu_exact(acc[m].w + bv.w);
            *((float4*)&ht[m * 8 + g][c]) = hv;
        }
    }
    __syncthreads();

    // phase 2: y = h@W2 + b2 + x; 32 col-groups x 12 node-groups (rows m*12+g, m=0..1)
    {
        const int ct = tid % 32, g = tid / 32;
        const int c = ct * 4;
        float4 acc[2];
        #pragma unroll
        for (int m = 0; m < 2; ++m) acc[m] = make_float4(0.f, 0.f, 0.f, 0.f);
        for (int k4 = 0; k4 < 192; k4 += 4) {
            float4 f[2];
            #pragma unroll
            for (int m = 0; m < 2; ++m) f[m] = *((const float4*)&ht[m * 12 + g][k4]);
            #pragma unroll
            for (int kk = 0; kk < 4; ++kk) {
                float4 w = *((const float4*)(W2 + (size_t)(k4 + kk) * 128 + c));
                #pragma unroll
                for (int m = 0; m < 2; ++m) fma4(acc[m], getc(f[m], kk), w);
            }
        }
        const float4 bv = *((const float4*)(b2 + c));
        #pragma unroll
        for (int m = 0; m < 2; ++m) {
            int rrow = m * 12 + g;
            float4 xr = *((const float4*)&xt[rrow][c]);
            float4 y;
            y.x = acc[m].x + bv.x + xr.x; y.y = acc[m].y + bv.y + xr.y;
            y.z = acc[m].z + bv.z + xr.z; y.w = acc[m].w + bv.w + xr.w;
            *((float4*)&yt[rrow][c]) = y;
        }
    }
    __syncthreads();

    // LN2: 16 threads per node
    const int m = tid >> 4, rr = tid & 15;
    float s = 0.f;
    #pragma unroll
    for (int i = 0; i < 8; ++i) s += yt[m][i * 16 + rr];
    #pragma unroll
    for (int msk = 1; msk < 16; msk <<= 1) s += __shfl_xor(s, msk, 16);
    const float mu = s * (1.0f / 128.0f);
    float s2 = 0.f;
    #pragma unroll
    for (int i = 0; i < 8; ++i) { float d = yt[m][i * 16 + rr] - mu; s2 = fmaf(d, d, s2); }
    #pragma unroll
    for (int msk = 1; msk < 16; msk <<= 1) s2 += __shfl_xor(s2, msk, 16);
    const float rs = rsqrtf(s2 * (1.0f / 128.0f) + 1e-5f);
    const int row = row0 + m;
    if (row < n) {
        #pragma unroll
        for (int i = 0; i < 8; ++i) {
            int cc = i * 16 + rr;
            out[(size_t)row * 128 + cc] = (yt[m][cc] - mu) * rs * g2[cc] + bl2[cc];
        }
    }
}

// ---------- launch ----------
extern "C" void kernel_launch(void* const* d_in, const int* in_sizes, int n_in,
                              void* d_out, int out_size, void* d_ws, size_t ws_size,
                              hipStream_t stream)
{
    const float* feat = (const float*)d_in[0];
    const int*   knn  = (const int*)d_in[1];
    const float* dist = (const float*)d_in[2];
    const float* Wq   = (const float*)d_in[3];
    const float* Wk   = (const float*)d_in[4];
    const float* Wv   = (const float*)d_in[5];
    const float* Wo   = (const float*)d_in[6];
    const float* bo   = (const float*)d_in[7];
    const float* g1   = (const float*)d_in[8];
    const float* b1ln = (const float*)d_in[9];
    const float* W1   = (const float*)d_in[10];
    const float* b1f  = (const float*)d_in[11];
    const float* W2   = (const float*)d_in[12];
    const float* b2f  = (const float*)d_in[13];
    const float* g2   = (const float*)d_in[14];
    const float* b2ln = (const float*)d_in[15];
    float* out = (float*)d_out;

    const int n = in_sizes[0] / 128;
    const size_t ND = (size_t)n * 128;
    if (ws_size < 4 * ND * sizeof(float)) return;   // insufficient scratch -> clean fail

    float* Q   = (float*)d_ws;
    float* Kp  = Q + ND;
    float* Vp  = Kp + ND;
    float* att = Vp + ND;                           // reused in-place as X after k_woln

    k_qkv <<<(n + 31) / 32, 384, 0, stream>>>(feat, Wq, Wk, Wv, Q, Kp, Vp, n);
    k_attn<<<(n + 3) / 4,  256, 0, stream>>>(Q, Kp, Vp, knn, dist, att, n);
    k_woln<<<(n + 31) / 32, 256, 0, stream>>>(att, Wo, bo, feat, g1, b1ln, att, n);
    k_ffn <<<(n + 23) / 24, 384, 0, stream>>>(att, W1, b1f, W2, b2f, g2, b2ln, out, n);
}

// Round 2
// 656.713 us; speedup vs baseline: 6.6381x; 6.6381x over previous
//
#include <hip/hip_runtime.h>
#include <cmath>

// ---------- helpers ----------
__device__ __forceinline__ void fma4(float4& a, float s, const float4& b) {
    a.x = fmaf(s, b.x, a.x); a.y = fmaf(s, b.y, a.y);
    a.z = fmaf(s, b.z, a.z); a.w = fmaf(s, b.w, a.w);
}
__device__ __forceinline__ float getc(const float4& v, int i) {
    return i == 0 ? v.x : (i == 1 ? v.y : (i == 2 ? v.z : v.w));
}
__device__ __forceinline__ float dot4(const float4& a, const float4& b) {
    return a.x*b.x + a.y*b.y + a.z*b.z + a.w*b.w;
}
__device__ __forceinline__ float gelu_exact(float v) {
    return 0.5f * v * (1.0f + erff(v * 0.70710678118654752440f));
}

// ---------- K1: Q/K/V projection, weights staged in LDS (64KB buffer reused 3x) ----
// block 256; tile 32 rows; thread owns 4 cols x 4 rows per matrix pass.
__global__ __launch_bounds__(256, 1) void k_qkv(
    const float* __restrict__ feat,
    const float* __restrict__ Wq, const float* __restrict__ Wk, const float* __restrict__ Wv,
    float* __restrict__ Q, float* __restrict__ Kp, float* __restrict__ Vp, int n)
{
    __shared__ float wld[128 * 128];           // 64 KB, reloaded per matrix
    __shared__ float ft[32][132];              // +4 pad
    const int tid = threadIdx.x;
    const int row0 = blockIdx.x * 32;

    for (int i = tid; i < 1024; i += 256) {    // 32 rows x 32 float4
        int m = i >> 5, kk = i & 31;
        float4 v = make_float4(0.f, 0.f, 0.f, 0.f);
        int row = row0 + m;
        if (row < n) v = ((const float4*)(feat + (size_t)row * 128))[kk];
        *((float4*)&ft[m][kk * 4]) = v;
    }

    const int ct = tid & 31, g = tid >> 5;     // c-group, row-slot
    const int c = ct * 4;

    for (int mat = 0; mat < 3; ++mat) {
        const float* W = (mat == 0) ? Wq : (mat == 1 ? Wk : Wv);
        float* O       = (mat == 0) ? Q  : (mat == 1 ? Kp : Vp);
        __syncthreads();                       // wld safe to overwrite (also covers ft on mat=0)
        for (int i = tid; i < 4096; i += 256)
            *((float4*)&wld[i * 4]) = ((const float4*)W)[i];
        __syncthreads();

        float4 acc[4];
        #pragma unroll
        for (int m = 0; m < 4; ++m) acc[m] = make_float4(0.f, 0.f, 0.f, 0.f);
        for (int k4 = 0; k4 < 128; k4 += 4) {
            float4 f[4];
            #pragma unroll
            for (int m = 0; m < 4; ++m) f[m] = *((const float4*)&ft[m * 8 + g][k4]);
            #pragma unroll
            for (int kk = 0; kk < 4; ++kk) {
                float4 w = *((const float4*)&wld[(k4 + kk) * 128 + c]);
                #pragma unroll
                for (int m = 0; m < 4; ++m) fma4(acc[m], getc(f[m], kk), w);
            }
        }
        #pragma unroll
        for (int m = 0; m < 4; ++m) {
            int row = row0 + m * 8 + g;
            if (row < n) *((float4*)(O + (size_t)row * 128 + c)) = acc[m];
        }
    }
}

// ---------- K2: KNN attention -> attended(N,128). one wave per node (unchanged) ----
__global__ __launch_bounds__(256, 1) void k_attn(
    const float* __restrict__ Q, const float* __restrict__ Kp, const float* __restrict__ Vp,
    const int* __restrict__ knn, const float* __restrict__ dist,
    float* __restrict__ att, int n)
{
    const int lane = threadIdx.x & 63;
    const int node = blockIdx.x * 4 + (threadIdx.x >> 6);
    if (node >= n) return;
    const int h = lane >> 3, r = lane & 7;

    const float* qp = Q + (size_t)node * 128 + h * 16;
    const float4 q0 = ((const float4*)qp)[0];
    const float4 q1 = ((const float4*)qp)[1];
    const float4 q2 = ((const float4*)qp)[2];
    const float4 q3 = ((const float4*)qp)[3];
    const float hs = exp2f(-(float)(h + 1));

    int idx[4]; float sd[4];
    #pragma unroll
    for (int jj = 0; jj < 4; ++jj) {
        int j = r + jj * 8;
        idx[jj] = knn[(size_t)node * 32 + j];
        sd[jj]  = dist[(size_t)node * 32 + j] * hs;
    }

    float ap[4], an[4];
    #pragma unroll
    for (int jj = 0; jj < 4; ++jj) {
        const float* kp = Kp + (size_t)idx[jj] * 128 + h * 16;
        float4 k0 = ((const float4*)kp)[0];
        float4 k1 = ((const float4*)kp)[1];
        float4 k2 = ((const float4*)kp)[2];
        float4 k3 = ((const float4*)kp)[3];
        float s = dot4(q0, k0) + dot4(q1, k1) + dot4(q2, k2) + dot4(q3, k3);
        float raw = s * 0.25f;
        ap[jj] = raw - sd[jj];
        an[jj] = (-raw - sd[jj]) * (1.0f / 0.6f);
    }

    float mp = fmaxf(fmaxf(ap[0], ap[1]), fmaxf(ap[2], ap[3]));
    float mn = fmaxf(fmaxf(an[0], an[1]), fmaxf(an[2], an[3]));
    #pragma unroll
    for (int msk = 1; msk < 8; msk <<= 1) {
        mp = fmaxf(mp, __shfl_xor(mp, msk, 8));
        mn = fmaxf(mn, __shfl_xor(mn, msk, 8));
    }
    float ep[4], en[4], sp = 0.f, sn = 0.f;
    #pragma unroll
    for (int jj = 0; jj < 4; ++jj) {
        ep[jj] = expf(ap[jj] - mp); sp += ep[jj];
        en[jj] = expf(an[jj] - mn); sn += en[jj];
    }
    #pragma unroll
    for (int msk = 1; msk < 8; msk <<= 1) {
        sp += __shfl_xor(sp, msk, 8);
        sn += __shfl_xor(sn, msk, 8);
    }
    const float isp = 1.0f / sp;
    const float isn = 1.5f / sn;

    float4 a0 = make_float4(0,0,0,0), a1 = a0, a2 = a0, a3 = a0;
    #pragma unroll
    for (int jj = 0; jj < 4; ++jj) {
        float w = ep[jj] * isp - en[jj] * isn;
        const float* vp = Vp + (size_t)idx[jj] * 128 + h * 16;
        float4 v0 = ((const float4*)vp)[0];
        float4 v1 = ((const float4*)vp)[1];
        float4 v2 = ((const float4*)vp)[2];
        float4 v3 = ((const float4*)vp)[3];
        fma4(a0, w, v0); fma4(a1, w, v1); fma4(a2, w, v2); fma4(a3, w, v3);
    }
    #pragma unroll
    for (int msk = 1; msk < 8; msk <<= 1) {
        a0.x += __shfl_xor(a0.x, msk, 8); a0.y += __shfl_xor(a0.y, msk, 8);
        a0.z += __shfl_xor(a0.z, msk, 8); a0.w += __shfl_xor(a0.w, msk, 8);
        a1.x += __shfl_xor(a1.x, msk, 8); a1.y += __shfl_xor(a1.y, msk, 8);
        a1.z += __shfl_xor(a1.z, msk, 8); a1.w += __shfl_xor(a1.w, msk, 8);
        a2.x += __shfl_xor(a2.x, msk, 8); a2.y += __shfl_xor(a2.y, msk, 8);
        a2.z += __shfl_xor(a2.z, msk, 8); a2.w += __shfl_xor(a2.w, msk, 8);
        a3.x += __shfl_xor(a3.x, msk, 8); a3.y += __shfl_xor(a3.y, msk, 8);
        a3.z += __shfl_xor(a3.z, msk, 8); a3.w += __shfl_xor(a3.w, msk, 8);
    }
    if (r == 0) {
        float* op = att + (size_t)node * 128 + h * 16;
        ((float4*)op)[0] = a0; ((float4*)op)[1] = a1;
        ((float4*)op)[2] = a2; ((float4*)op)[3] = a3;
    }
}

// ---------- K3: x = LN1(att @ Wo + bo + feat); Wo staged in LDS ----------
__global__ __launch_bounds__(256, 1) void k_woln(
    const float* __restrict__ att, const float* __restrict__ Wo,
    const float* __restrict__ bo, const float* __restrict__ feat,
    const float* __restrict__ g1, const float* __restrict__ b1,
    float* __restrict__ X, int n)
{
    __shared__ float wld[128 * 128];           // 64 KB
    __shared__ float at[32][132];
    __shared__ float yt[32][132];
    const int tid = threadIdx.x;
    const int row0 = blockIdx.x * 32;

    for (int i = tid; i < 4096; i += 256)
        *((float4*)&wld[i * 4]) = ((const float4*)Wo)[i];
    for (int i = tid; i < 1024; i += 256) {
        int m = i >> 5, kk = i & 31;
        float4 v = make_float4(0.f, 0.f, 0.f, 0.f);
        int row = row0 + m;
        if (row < n) v = ((const float4*)(att + (size_t)row * 128))[kk];
        *((float4*)&at[m][kk * 4]) = v;
    }
    __syncthreads();

    const int ct = tid & 31, g = tid >> 5;
    const int c = ct * 4;
    float4 acc[4];
    #pragma unroll
    for (int m = 0; m < 4; ++m) acc[m] = make_float4(0.f, 0.f, 0.f, 0.f);
    for (int k4 = 0; k4 < 128; k4 += 4) {
        float4 f[4];
        #pragma unroll
        for (int m = 0; m < 4; ++m) f[m] = *((const float4*)&at[m * 8 + g][k4]);
        #pragma unroll
        for (int kk = 0; kk < 4; ++kk) {
            float4 w = *((const float4*)&wld[(k4 + kk) * 128 + c]);
            #pragma unroll
            for (int m = 0; m < 4; ++m) fma4(acc[m], getc(f[m], kk), w);
        }
    }
    const float4 bv = *((const float4*)(bo + c));
    #pragma unroll
    for (int m = 0; m < 4; ++m) {
        int row = row0 + m * 8 + g;
        float4 fr = make_float4(0.f, 0.f, 0.f, 0.f);
        if (row < n) fr = *((const float4*)(feat + (size_t)row * 128 + c));
        float4 y;
        y.x = acc[m].x + bv.x + fr.x; y.y = acc[m].y + bv.y + fr.y;
        y.z = acc[m].z + bv.z + fr.z; y.w = acc[m].w + bv.w + fr.w;
        *((float4*)&yt[m * 8 + g][c]) = y;
    }
    __syncthreads();

    const int m = tid >> 3, rr = tid & 7;      // 8 threads per node
    float s = 0.f;
    #pragma unroll
    for (int i = 0; i < 16; ++i) s += yt[m][i * 8 + rr];
    #pragma unroll
    for (int msk = 1; msk < 8; msk <<= 1) s += __shfl_xor(s, msk, 8);
    const float mu = s * (1.0f / 128.0f);
    float s2 = 0.f;
    #pragma unroll
    for (int i = 0; i < 16; ++i) { float d = yt[m][i * 8 + rr] - mu; s2 = fmaf(d, d, s2); }
    #pragma unroll
    for (int msk = 1; msk < 8; msk <<= 1) s2 += __shfl_xor(s2, msk, 8);
    const float rs = rsqrtf(s2 * (1.0f / 128.0f) + 1e-5f);
    const int row = row0 + m;
    if (row < n) {
        #pragma unroll
        for (int i = 0; i < 16; ++i) {
            int cc = i * 8 + rr;
            X[(size_t)row * 128 + cc] = (yt[m][cc] - mu) * rs * g1[cc] + b1[cc];
        }
    }
}

// ---------- K4a: H = gelu(X@W1 + b1); W1 (98 KB) staged in LDS ----------
__global__ __launch_bounds__(384, 1) void k_ffn1(
    const float* __restrict__ X, const float* __restrict__ W1, const float* __restrict__ b1,
    float* __restrict__ Hout, int n)
{
    __shared__ float wld[128 * 192];           // 98304 B
    __shared__ float xt[32][132];              // 16896 B  (total 115200)
    const int tid = threadIdx.x;
    const int row0 = blockIdx.x * 32;

    for (int i = tid; i < 6144; i += 384)
        *((float4*)&wld[i * 4]) = ((const float4*)W1)[i];
    for (int i = tid; i < 1024; i += 384) {
        int m = i >> 5, kk = i & 31;
        float4 v = make_float4(0.f, 0.f, 0.f, 0.f);
        int row = row0 + m;
        if (row < n) v = ((const float4*)(X + (size_t)row * 128))[kk];
        *((float4*)&xt[m][kk * 4]) = v;
    }
    __syncthreads();

    const int ct = tid % 48, g = tid / 48;     // 48 col-groups x 8 row-slots
    const int c = ct * 4;
    float4 acc[4];
    #pragma unroll
    for (int m = 0; m < 4; ++m) acc[m] = make_float4(0.f, 0.f, 0.f, 0.f);
    for (int k4 = 0; k4 < 128; k4 += 4) {
        float4 f[4];
        #pragma unroll
        for (int m = 0; m < 4; ++m) f[m] = *((const float4*)&xt[m * 8 + g][k4]);
        #pragma unroll
        for (int kk = 0; kk < 4; ++kk) {
            float4 w = *((const float4*)&wld[(k4 + kk) * 192 + c]);
            #pragma unroll
            for (int m = 0; m < 4; ++m) fma4(acc[m], getc(f[m], kk), w);
        }
    }
    const float4 bv = *((const float4*)(b1 + c));
    #pragma unroll
    for (int m = 0; m < 4; ++m) {
        int row = row0 + m * 8 + g;
        if (row < n) {
            float4 hv;
            hv.x = gelu_exact(acc[m].x + bv.x);
            hv.y = gelu_exact(acc[m].y + bv.y);
            hv.z = gelu_exact(acc[m].z + bv.z);
            hv.w = gelu_exact(acc[m].w + bv.w);
            *((float4*)(Hout + (size_t)row * 192 + c)) = hv;
        }
    }
}

// ---------- K4b: out = LN2(H@W2 + b2 + X); W2 (98 KB) staged in LDS ----------
__global__ __launch_bounds__(256, 1) void k_ffn2(
    const float* __restrict__ H, const float* __restrict__ X,
    const float* __restrict__ W2, const float* __restrict__ b2,
    const float* __restrict__ g2, const float* __restrict__ bl2,
    float* __restrict__ out, int n)
{
    __shared__ float wld[192 * 128];           // 98304 B
    __shared__ float ht[32][196];              // 25088 B
    __shared__ float yt[32][132];              // 16896 B (total 140288)
    const int tid = threadIdx.x;
    const int row0 = blockIdx.x * 32;

    for (int i = tid; i < 6144; i += 256)
        *((float4*)&wld[i * 4]) = ((const float4*)W2)[i];
    for (int i = tid; i < 1536; i += 256) {    // 32 rows x 48 float4
        int m = i / 48, kk = i % 48;
        float4 v = make_float4(0.f, 0.f, 0.f, 0.f);
        int row = row0 + m;
        if (row < n) v = ((const float4*)(H + (size_t)row * 192))[kk];
        *((float4*)&ht[m][kk * 4]) = v;
    }
    __syncthreads();

    const int ct = tid & 31, g = tid >> 5;
    const int c = ct * 4;
    float4 acc[4];
    #pragma unroll
    for (int m = 0; m < 4; ++m) acc[m] = make_float4(0.f, 0.f, 0.f, 0.f);
    for (int k4 = 0; k4 < 192; k4 += 4) {
        float4 f[4];
        #pragma unroll
        for (int m = 0; m < 4; ++m) f[m] = *((const float4*)&ht[m * 8 + g][k4]);
        #pragma unroll
        for (int kk = 0; kk < 4; ++kk) {
            float4 w = *((const float4*)&wld[(k4 + kk) * 128 + c]);
            #pragma unroll
            for (int m = 0; m < 4; ++m) fma4(acc[m], getc(f[m], kk), w);
        }
    }
    const float4 bv = *((const float4*)(b2 + c));
    #pragma unroll
    for (int m = 0; m < 4; ++m) {
        int row = row0 + m * 8 + g;
        float4 xr = make_float4(0.f, 0.f, 0.f, 0.f);
        if (row < n) xr = *((const float4*)(X + (size_t)row * 128 + c));
        float4 y;
        y.x = acc[m].x + bv.x + xr.x; y.y = acc[m].y + bv.y + xr.y;
        y.z = acc[m].z + bv.z + xr.z; y.w = acc[m].w + bv.w + xr.w;
        *((float4*)&yt[m * 8 + g][c]) = y;
    }
    __syncthreads();

    const int m = tid >> 3, rr = tid & 7;      // 8 threads per node
    float s = 0.f;
    #pragma unroll
    for (int i = 0; i < 16; ++i) s += yt[m][i * 8 + rr];
    #pragma unroll
    for (int msk = 1; msk < 8; msk <<= 1) s += __shfl_xor(s, msk, 8);
    const float mu = s * (1.0f / 128.0f);
    float s2 = 0.f;
    #pragma unroll
    for (int i = 0; i < 16; ++i) { float d = yt[m][i * 8 + rr] - mu; s2 = fmaf(d, d, s2); }
    #pragma unroll
    for (int msk = 1; msk < 8; msk <<= 1) s2 += __shfl_xor(s2, msk, 8);
    const float rs = rsqrtf(s2 * (1.0f / 128.0f) + 1e-5f);
    const int row = row0 + m;
    if (row < n) {
        #pragma unroll
        for (int i = 0; i < 16; ++i) {
            int cc = i * 8 + rr;
            out[(size_t)row * 128 + cc] = (yt[m][cc] - mu) * rs * g2[cc] + bl2[cc];
        }
    }
}

// ---------- launch ----------
extern "C" void kernel_launch(void* const* d_in, const int* in_sizes, int n_in,
                              void* d_out, int out_size, void* d_ws, size_t ws_size,
                              hipStream_t stream)
{
    const float* feat = (const float*)d_in[0];
    const int*   knn  = (const int*)d_in[1];
    const float* dist = (const float*)d_in[2];
    const float* Wq   = (const float*)d_in[3];
    const float* Wk   = (const float*)d_in[4];
    const float* Wv   = (const float*)d_in[5];
    const float* Wo   = (const float*)d_in[6];
    const float* bo   = (const float*)d_in[7];
    const float* g1   = (const float*)d_in[8];
    const float* b1ln = (const float*)d_in[9];
    const float* W1   = (const float*)d_in[10];
    const float* b1f  = (const float*)d_in[11];
    const float* W2   = (const float*)d_in[12];
    const float* b2f  = (const float*)d_in[13];
    const float* g2   = (const float*)d_in[14];
    const float* b2ln = (const float*)d_in[15];
    float* out = (float*)d_out;

    const int n = in_sizes[0] / 128;
    const size_t ND = (size_t)n * 128;
    if (ws_size < 4 * ND * sizeof(float)) return;

    float* Q   = (float*)d_ws;
    float* Kp  = Q + ND;
    float* Vp  = Kp + ND;
    float* att = Vp + ND;            // becomes X after k_woln (in-place)
    float* Hbuf = Q;                 // Q/Kp dead after k_attn; H = N x 192 fits in 2*ND

    const int tiles = (n + 31) / 32;
    k_qkv <<<tiles, 256, 0, stream>>>(feat, Wq, Wk, Wv, Q, Kp, Vp, n);
    k_attn<<<(n + 3) / 4, 256, 0, stream>>>(Q, Kp, Vp, knn, dist, att, n);
    k_woln<<<tiles, 256, 0, stream>>>(att, Wo, bo, feat, g1, b1ln, att, n);
    k_ffn1<<<tiles, 384, 0, stream>>>(att, W1, b1f, Hbuf, n);
    k_ffn2<<<tiles, 256, 0, stream>>>(Hbuf, att, W2, b2f, g2, b2ln, out, n);
}

// Round 3
// 306.614 us; speedup vs baseline: 14.2177x; 2.1418x over previous
//
#include <hip/hip_runtime.h>
#include <cmath>

typedef __attribute__((ext_vector_type(8))) short bf16x8;
typedef __attribute__((ext_vector_type(4))) float f32x4;

__device__ __forceinline__ unsigned short f2bf(float x) {
    unsigned int u = __float_as_uint(x);
    u += 0x7fffu + ((u >> 16) & 1u);
    return (unsigned short)(u >> 16);
}
__device__ __forceinline__ float bflo(unsigned int u) { return __uint_as_float(u << 16); }
__device__ __forceinline__ float bfhi(unsigned int u) { return __uint_as_float(u & 0xffff0000u); }
__device__ __forceinline__ float gelu_exact(float v) {
    return 0.5f * v * (1.0f + erff(v * 0.70710678118654752440f));
}

// ============ K0: weight prep — fp32 -> bf16, MFMA-B-fragment order ============
// frag(ct,ks,l,j) = W[ks*32 + (l>>4)*8 + j][ct*16 + (l&15)]; flat = ((ct*KS+ks)*64+l)*8+j
// ws layout (shorts): Wq@0 Wk@16384 Wv@32768 Wo@49152 W1@65536 W2@90112  (total 114688)
__global__ __launch_bounds__(256, 1) void k_prep(
    const float* __restrict__ Wq, const float* __restrict__ Wk, const float* __restrict__ Wv,
    const float* __restrict__ Wo, const float* __restrict__ W1, const float* __restrict__ W2,
    unsigned short* __restrict__ wsz)
{
    int f = blockIdx.x * 256 + threadIdx.x;
    const float* W; unsigned short* dst; int M, KS, fl;
    if (f < 2048)       { W = Wq; dst = wsz;         M = 128; KS = 4; fl = f; }
    else if (f < 4096)  { W = Wk; dst = wsz + 16384; M = 128; KS = 4; fl = f - 2048; }
    else if (f < 6144)  { W = Wv; dst = wsz + 32768; M = 128; KS = 4; fl = f - 4096; }
    else if (f < 8192)  { W = Wo; dst = wsz + 49152; M = 128; KS = 4; fl = f - 6144; }
    else if (f < 11264) { W = W1; dst = wsz + 65536; M = 192; KS = 4; fl = f - 8192; }
    else if (f < 14336) { W = W2; dst = wsz + 90112; M = 128; KS = 6; fl = f - 11264; }
    else return;
    const int l  = fl & 63;
    const int ks = (fl >> 6) % KS;
    const int ct = (fl >> 6) / KS;
    const int k0 = ks * 32 + (l >> 4) * 8;
    const int col = ct * 16 + (l & 15);
    unsigned short tmp[8];
    #pragma unroll
    for (int j = 0; j < 8; ++j) tmp[j] = f2bf(W[(size_t)(k0 + j) * M + col]);
    ((uint4*)dst)[fl] = *(uint4*)tmp;
}

// ============ K1: QKV projection (MFMA). 64 rows/block, 4 waves, 24 col-tiles ====
// Q written fp32; K,V written bf16 (halves the attention gather bytes).
__global__ __launch_bounds__(256, 1) void k_qkv(
    const float* __restrict__ feat, const unsigned short* __restrict__ wsz,
    float* __restrict__ Q, unsigned short* __restrict__ Kb, unsigned short* __restrict__ Vb, int n)
{
    __shared__ __align__(16) unsigned short bw[3 * 16384];   // 96 KB: Wq|Wk|Wv swizzled
    __shared__ __align__(16) unsigned short at[64 * 136];    // 17.4 KB, stride 136
    const int tid = threadIdx.x;
    const int row0 = blockIdx.x * 64;

    for (int i = tid; i < 6144; i += 256)
        ((uint4*)bw)[i] = ((const uint4*)wsz)[i];
    for (int i = tid; i < 2048; i += 256) {                   // 64 rows x 32 float4
        int row = i >> 5, col = (i & 31) * 4;
        float4 v = make_float4(0.f, 0.f, 0.f, 0.f);
        int gr = row0 + row;
        if (gr < n) v = ((const float4*)(feat + (size_t)gr * 128))[i & 31];
        unsigned int u0 = (unsigned int)f2bf(v.x) | ((unsigned int)f2bf(v.y) << 16);
        unsigned int u1 = (unsigned int)f2bf(v.z) | ((unsigned int)f2bf(v.w) << 16);
        *((uint2*)&at[row * 136 + col]) = make_uint2(u0, u1);
    }
    __syncthreads();

    const int w = tid >> 6, lane = tid & 63;
    const int lrow = lane & 15, kgrp = lane >> 4;

    bf16x8 a[4];
    #pragma unroll
    for (int ks = 0; ks < 4; ++ks)
        a[ks] = *(const bf16x8*)&at[(w * 16 + lrow) * 136 + ks * 32 + kgrp * 8];

    f32x4 acc[24];
    #pragma unroll
    for (int ct = 0; ct < 24; ++ct) acc[ct] = (f32x4){0.f, 0.f, 0.f, 0.f};
    #pragma unroll
    for (int ct = 0; ct < 24; ++ct) {
        #pragma unroll
        for (int ks = 0; ks < 4; ++ks) {
            bf16x8 b = *(const bf16x8*)&bw[((ct * 4 + ks) * 64 + lane) * 8];
            acc[ct] = __builtin_amdgcn_mfma_f32_16x16x32_bf16(a[ks], b, acc[ct], 0, 0, 0);
        }
    }

    const int orow0 = row0 + w * 16 + kgrp * 4;
    #pragma unroll
    for (int ct = 0; ct < 24; ++ct) {
        const int col = (ct & 7) * 16 + lrow;
        #pragma unroll
        for (int rr = 0; rr < 4; ++rr) {
            int gr = orow0 + rr;
            if (gr < n) {
                if (ct < 8)       Q [(size_t)gr * 128 + col] = acc[ct][rr];
                else if (ct < 16) Kb[(size_t)gr * 128 + col] = f2bf(acc[ct][rr]);
                else              Vb[(size_t)gr * 128 + col] = f2bf(acc[ct][rr]);
            }
        }
    }
}

// ============ K2: KNN attention, bf16 K/V gather. one wave per node =============
__global__ __launch_bounds__(256, 1) void k_attn(
    const float* __restrict__ Q, const unsigned short* __restrict__ Kb,
    const unsigned short* __restrict__ Vb,
    const int* __restrict__ knn, const float* __restrict__ dist,
    float* __restrict__ att, int n)
{
    const int lane = threadIdx.x & 63;
    const int node = blockIdx.x * 4 + (threadIdx.x >> 6);
    if (node >= n) return;
    const int h = lane >> 3, r = lane & 7;

    const float* qp = Q + (size_t)node * 128 + h * 16;
    float q[16];
    *(float4*)&q[0]  = ((const float4*)qp)[0];
    *(float4*)&q[4]  = ((const float4*)qp)[1];
    *(float4*)&q[8]  = ((const float4*)qp)[2];
    *(float4*)&q[12] = ((const float4*)qp)[3];
    const float hs = exp2f(-(float)(h + 1));

    int idx[4]; float sd[4];
    #pragma unroll
    for (int jj = 0; jj < 4; ++jj) {
        int j = r + jj * 8;
        idx[jj] = knn[(size_t)node * 32 + j];
        sd[jj]  = dist[(size_t)node * 32 + j] * hs;
    }

    float ap[4], an[4];
    #pragma unroll
    for (int jj = 0; jj < 4; ++jj) {
        const unsigned short* kp = Kb + (size_t)idx[jj] * 128 + h * 16;
        uint4 u0 = *(const uint4*)kp;
        uint4 u1 = *(const uint4*)(kp + 8);
        float s = 0.f;
        s = fmaf(q[0],  bflo(u0.x), s); s = fmaf(q[1],  bfhi(u0.x), s);
        s = fmaf(q[2],  bflo(u0.y), s); s = fmaf(q[3],  bfhi(u0.y), s);
        s = fmaf(q[4],  bflo(u0.z), s); s = fmaf(q[5],  bfhi(u0.z), s);
        s = fmaf(q[6],  bflo(u0.w), s); s = fmaf(q[7],  bfhi(u0.w), s);
        s = fmaf(q[8],  bflo(u1.x), s); s = fmaf(q[9],  bfhi(u1.x), s);
        s = fmaf(q[10], bflo(u1.y), s); s = fmaf(q[11], bfhi(u1.y), s);
        s = fmaf(q[12], bflo(u1.z), s); s = fmaf(q[13], bfhi(u1.z), s);
        s = fmaf(q[14], bflo(u1.w), s); s = fmaf(q[15], bfhi(u1.w), s);
        float raw = s * 0.25f;
        ap[jj] = raw - sd[jj];
        an[jj] = (-raw - sd[jj]) * (1.0f / 0.6f);
    }

    float mp = fmaxf(fmaxf(ap[0], ap[1]), fmaxf(ap[2], ap[3]));
    float mn = fmaxf(fmaxf(an[0], an[1]), fmaxf(an[2], an[3]));
    #pragma unroll
    for (int msk = 1; msk < 8; msk <<= 1) {
        mp = fmaxf(mp, __shfl_xor(mp, msk, 8));
        mn = fmaxf(mn, __shfl_xor(mn, msk, 8));
    }
    float ep[4], en[4], sp = 0.f, sn = 0.f;
    #pragma unroll
    for (int jj = 0; jj < 4; ++jj) {
        ep[jj] = expf(ap[jj] - mp); sp += ep[jj];
        en[jj] = expf(an[jj] - mn); sn += en[jj];
    }
    #pragma unroll
    for (int msk = 1; msk < 8; msk <<= 1) {
        sp += __shfl_xor(sp, msk, 8);
        sn += __shfl_xor(sn, msk, 8);
    }
    const float isp = 1.0f / sp;
    const float isn = 1.5f / sn;

    float acc[16];
    #pragma unroll
    for (int i = 0; i < 16; ++i) acc[i] = 0.f;
    #pragma unroll
    for (int jj = 0; jj < 4; ++jj) {
        float wgt = ep[jj] * isp - en[jj] * isn;
        const unsigned short* vp = Vb + (size_t)idx[jj] * 128 + h * 16;
        uint4 u0 = *(const uint4*)vp;
        uint4 u1 = *(const uint4*)(vp + 8);
        acc[0]  = fmaf(wgt, bflo(u0.x), acc[0]);  acc[1]  = fmaf(wgt, bfhi(u0.x), acc[1]);
        acc[2]  = fmaf(wgt, bflo(u0.y), acc[2]);  acc[3]  = fmaf(wgt, bfhi(u0.y), acc[3]);
        acc[4]  = fmaf(wgt, bflo(u0.z), acc[4]);  acc[5]  = fmaf(wgt, bfhi(u0.z), acc[5]);
        acc[6]  = fmaf(wgt, bflo(u0.w), acc[6]);  acc[7]  = fmaf(wgt, bfhi(u0.w), acc[7]);
        acc[8]  = fmaf(wgt, bflo(u1.x), acc[8]);  acc[9]  = fmaf(wgt, bfhi(u1.x), acc[9]);
        acc[10] = fmaf(wgt, bflo(u1.y), acc[10]); acc[11] = fmaf(wgt, bfhi(u1.y), acc[11]);
        acc[12] = fmaf(wgt, bflo(u1.z), acc[12]); acc[13] = fmaf(wgt, bfhi(u1.z), acc[13]);
        acc[14] = fmaf(wgt, bflo(u1.w), acc[14]); acc[15] = fmaf(wgt, bfhi(u1.w), acc[15]);
    }
    #pragma unroll
    for (int i = 0; i < 16; ++i) {
        #pragma unroll
        for (int msk = 1; msk < 8; msk <<= 1) acc[i] += __shfl_xor(acc[i], msk, 8);
    }
    if (r == 0) {
        float* op = att + (size_t)node * 128 + h * 16;
        ((float4*)op)[0] = *(float4*)&acc[0];
        ((float4*)op)[1] = *(float4*)&acc[4];
        ((float4*)op)[2] = *(float4*)&acc[8];
        ((float4*)op)[3] = *(float4*)&acc[12];
    }
}

// ============ K3: X = LN1(att@Wo + bo + feat), in-register LN, X over att =======
// 128 rows/block, 4 waves x 2 row-tiles; 8 col-tiles.
__global__ __launch_bounds__(256, 1) void k_woln(
    const float* __restrict__ att, const unsigned short* __restrict__ wsz,
    const float* __restrict__ bo, const float* __restrict__ feat,
    const float* __restrict__ g1, const float* __restrict__ b1,
    float* __restrict__ X, int n)
{
    __shared__ __align__(16) unsigned short bw[16384];        // 32 KB (Wo swz)
    __shared__ __align__(16) unsigned short at[128 * 136];    // 34.8 KB
    const int tid = threadIdx.x;
    const int row0 = blockIdx.x * 128;
    const unsigned short* wo = wsz + 49152;

    for (int i = tid; i < 2048; i += 256)
        ((uint4*)bw)[i] = ((const uint4*)wo)[i];
    for (int i = tid; i < 4096; i += 256) {                   // 128 rows x 32 float4
        int row = i >> 5, col = (i & 31) * 4;
        float4 v = make_float4(0.f, 0.f, 0.f, 0.f);
        int gr = row0 + row;
        if (gr < n) v = ((const float4*)(att + (size_t)gr * 128))[i & 31];
        unsigned int u0 = (unsigned int)f2bf(v.x) | ((unsigned int)f2bf(v.y) << 16);
        unsigned int u1 = (unsigned int)f2bf(v.z) | ((unsigned int)f2bf(v.w) << 16);
        *((uint2*)&at[row * 136 + col]) = make_uint2(u0, u1);
    }
    __syncthreads();

    const int w = tid >> 6, lane = tid & 63;
    const int lrow = lane & 15, kgrp = lane >> 4;

    bf16x8 a[2][4];
    #pragma unroll
    for (int rt = 0; rt < 2; ++rt)
        #pragma unroll
        for (int ks = 0; ks < 4; ++ks)
            a[rt][ks] = *(const bf16x8*)&at[(w * 32 + rt * 16 + lrow) * 136 + ks * 32 + kgrp * 8];

    f32x4 acc[2][8];
    #pragma unroll
    for (int rt = 0; rt < 2; ++rt)
        #pragma unroll
        for (int ct = 0; ct < 8; ++ct) acc[rt][ct] = (f32x4){0.f, 0.f, 0.f, 0.f};
    #pragma unroll
    for (int ct = 0; ct < 8; ++ct) {
        #pragma unroll
        for (int ks = 0; ks < 4; ++ks) {
            bf16x8 b = *(const bf16x8*)&bw[((ct * 4 + ks) * 64 + lane) * 8];
            #pragma unroll
            for (int rt = 0; rt < 2; ++rt)
                acc[rt][ct] = __builtin_amdgcn_mfma_f32_16x16x32_bf16(a[rt][ks], b, acc[rt][ct], 0, 0, 0);
        }
    }

    #pragma unroll
    for (int rt = 0; rt < 2; ++rt) {
        const int rbase = row0 + w * 32 + rt * 16 + kgrp * 4;
        #pragma unroll
        for (int ct = 0; ct < 8; ++ct) {
            const int col = ct * 16 + lrow;
            const float bov = bo[col];
            #pragma unroll
            for (int rr = 0; rr < 4; ++rr) {
                int gr = rbase + rr;
                float fr = (gr < n) ? feat[(size_t)gr * 128 + col] : 0.f;
                acc[rt][ct][rr] += bov + fr;
            }
        }
        float mu[4], rs[4];
        #pragma unroll
        for (int rr = 0; rr < 4; ++rr) {
            float s = 0.f;
            #pragma unroll
            for (int ct = 0; ct < 8; ++ct) s += acc[rt][ct][rr];
            #pragma unroll
            for (int msk = 1; msk < 16; msk <<= 1) s += __shfl_xor(s, msk, 16);
            mu[rr] = s * (1.0f / 128.0f);
        }
        #pragma unroll
        for (int rr = 0; rr < 4; ++rr) {
            float s2 = 0.f;
            #pragma unroll
            for (int ct = 0; ct < 8; ++ct) { float d = acc[rt][ct][rr] - mu[rr]; s2 = fmaf(d, d, s2); }
            #pragma unroll
            for (int msk = 1; msk < 16; msk <<= 1) s2 += __shfl_xor(s2, msk, 16);
            rs[rr] = rsqrtf(s2 * (1.0f / 128.0f) + 1e-5f);
        }
        #pragma unroll
        for (int ct = 0; ct < 8; ++ct) {
            const int col = ct * 16 + lrow;
            const float gg = g1[col], bb = b1[col];
            #pragma unroll
            for (int rr = 0; rr < 4; ++rr) {
                int gr = rbase + rr;
                if (gr < n)
                    X[(size_t)gr * 128 + col] = (acc[rt][ct][rr] - mu[rr]) * rs[rr] * gg + bb;
            }
        }
    }
}

// ============ K4a: H = gelu(X@W1 + b1)  -> bf16  ================================
__global__ __launch_bounds__(256, 1) void k_ffn1(
    const float* __restrict__ X, const unsigned short* __restrict__ wsz,
    const float* __restrict__ b1f, unsigned short* __restrict__ Hb, int n)
{
    __shared__ __align__(16) unsigned short bw[24576];        // 48 KB (W1 swz)
    __shared__ __align__(16) unsigned short at[128 * 136];
    const int tid = threadIdx.x;
    const int row0 = blockIdx.x * 128;
    const unsigned short* w1 = wsz + 65536;

    for (int i = tid; i < 3072; i += 256)
        ((uint4*)bw)[i] = ((const uint4*)w1)[i];
    for (int i = tid; i < 4096; i += 256) {
        int row = i >> 5, col = (i & 31) * 4;
        float4 v = make_float4(0.f, 0.f, 0.f, 0.f);
        int gr = row0 + row;
        if (gr < n) v = ((const float4*)(X + (size_t)gr * 128))[i & 31];
        unsigned int u0 = (unsigned int)f2bf(v.x) | ((unsigned int)f2bf(v.y) << 16);
        unsigned int u1 = (unsigned int)f2bf(v.z) | ((unsigned int)f2bf(v.w) << 16);
        *((uint2*)&at[row * 136 + col]) = make_uint2(u0, u1);
    }
    __syncthreads();

    const int w = tid >> 6, lane = tid & 63;
    const int lrow = lane & 15, kgrp = lane >> 4;

    bf16x8 a[2][4];
    #pragma unroll
    for (int rt = 0; rt < 2; ++rt)
        #pragma unroll
        for (int ks = 0; ks < 4; ++ks)
            a[rt][ks] = *(const bf16x8*)&at[(w * 32 + rt * 16 + lrow) * 136 + ks * 32 + kgrp * 8];

    f32x4 acc[2][12];
    #pragma unroll
    for (int rt = 0; rt < 2; ++rt)
        #pragma unroll
        for (int ct = 0; ct < 12; ++ct) acc[rt][ct] = (f32x4){0.f, 0.f, 0.f, 0.f};
    #pragma unroll
    for (int ct = 0; ct < 12; ++ct) {
        #pragma unroll
        for (int ks = 0; ks < 4; ++ks) {
            bf16x8 b = *(const bf16x8*)&bw[((ct * 4 + ks) * 64 + lane) * 8];
            #pragma unroll
            for (int rt = 0; rt < 2; ++rt)
                acc[rt][ct] = __builtin_amdgcn_mfma_f32_16x16x32_bf16(a[rt][ks], b, acc[rt][ct], 0, 0, 0);
        }
    }

    #pragma unroll
    for (int rt = 0; rt < 2; ++rt) {
        const int rbase = row0 + w * 32 + rt * 16 + kgrp * 4;
        #pragma unroll
        for (int ct = 0; ct < 12; ++ct) {
            const int col = ct * 16 + lrow;
            const float bv = b1f[col];
            #pragma unroll
            for (int rr = 0; rr < 4; ++rr) {
                int gr = rbase + rr;
                if (gr < n)
                    Hb[(size_t)gr * 192 + col] = f2bf(gelu_exact(acc[rt][ct][rr] + bv));
            }
        }
    }
}

// ============ K4b: out = LN2(H@W2 + b2 + X), in-register LN =====================
__global__ __launch_bounds__(256, 1) void k_ffn2(
    const unsigned short* __restrict__ Hb, const float* __restrict__ X,
    const unsigned short* __restrict__ wsz, const float* __restrict__ b2f,
    const float* __restrict__ g2, const float* __restrict__ bl2,
    float* __restrict__ out, int n)
{
    __shared__ __align__(16) unsigned short bw[24576];        // 48 KB (W2 swz)
    __shared__ __align__(16) unsigned short at[128 * 200];    // 51.2 KB, stride 200
    const int tid = threadIdx.x;
    const int row0 = blockIdx.x * 128;
    const unsigned short* w2 = wsz + 90112;

    for (int i = tid; i < 3072; i += 256)
        ((uint4*)bw)[i] = ((const uint4*)w2)[i];
    for (int i = tid; i < 3072; i += 256) {                   // 128 rows x 24 ushort8
        int row = i / 24, cg = i % 24;
        int gr = row0 + row;
        uint4 v = make_uint4(0u, 0u, 0u, 0u);
        if (gr < n) v = *(const uint4*)(Hb + (size_t)gr * 192 + cg * 8);
        *((uint4*)&at[row * 200 + cg * 8]) = v;
    }
    __syncthreads();

    const int w = tid >> 6, lane = tid & 63;
    const int lrow = lane & 15, kgrp = lane >> 4;

    bf16x8 a[2][6];
    #pragma unroll
    for (int rt = 0; rt < 2; ++rt)
        #pragma unroll
        for (int ks = 0; ks < 6; ++ks)
            a[rt][ks] = *(const bf16x8*)&at[(w * 32 + rt * 16 + lrow) * 200 + ks * 32 + kgrp * 8];

    f32x4 acc[2][8];
    #pragma unroll
    for (int rt = 0; rt < 2; ++rt)
        #pragma unroll
        for (int ct = 0; ct < 8; ++ct) acc[rt][ct] = (f32x4){0.f, 0.f, 0.f, 0.f};
    #pragma unroll
    for (int ct = 0; ct < 8; ++ct) {
        #pragma unroll
        for (int ks = 0; ks < 6; ++ks) {
            bf16x8 b = *(const bf16x8*)&bw[((ct * 6 + ks) * 64 + lane) * 8];
            #pragma unroll
            for (int rt = 0; rt < 2; ++rt)
                acc[rt][ct] = __builtin_amdgcn_mfma_f32_16x16x32_bf16(a[rt][ks], b, acc[rt][ct], 0, 0, 0);
        }
    }

    #pragma unroll
    for (int rt = 0; rt < 2; ++rt) {
        const int rbase = row0 + w * 32 + rt * 16 + kgrp * 4;
        #pragma unroll
        for (int ct = 0; ct < 8; ++ct) {
            const int col = ct * 16 + lrow;
            const float bv = b2f[col];
            #pragma unroll
            for (int rr = 0; rr < 4; ++rr) {
                int gr = rbase + rr;
                float xr = (gr < n) ? X[(size_t)gr * 128 + col] : 0.f;
                acc[rt][ct][rr] += bv + xr;
            }
        }
        float mu[4], rs[4];
        #pragma unroll
        for (int rr = 0; rr < 4; ++rr) {
            float s = 0.f;
            #pragma unroll
            for (int ct = 0; ct < 8; ++ct) s += acc[rt][ct][rr];
            #pragma unroll
            for (int msk = 1; msk < 16; msk <<= 1) s += __shfl_xor(s, msk, 16);
            mu[rr] = s * (1.0f / 128.0f);
        }
        #pragma unroll
        for (int rr = 0; rr < 4; ++rr) {
            float s2 = 0.f;
            #pragma unroll
            for (int ct = 0; ct < 8; ++ct) { float d = acc[rt][ct][rr] - mu[rr]; s2 = fmaf(d, d, s2); }
            #pragma unroll
            for (int msk = 1; msk < 16; msk <<= 1) s2 += __shfl_xor(s2, msk, 16);
            rs[rr] = rsqrtf(s2 * (1.0f / 128.0f) + 1e-5f);
        }
        #pragma unroll
        for (int ct = 0; ct < 8; ++ct) {
            const int col = ct * 16 + lrow;
            const float gg = g2[col], bb = bl2[col];
            #pragma unroll
            for (int rr = 0; rr < 4; ++rr) {
                int gr = rbase + rr;
                if (gr < n)
                    out[(size_t)gr * 128 + col] = (acc[rt][ct][rr] - mu[rr]) * rs[rr] * gg + bb;
            }
        }
    }
}

// ============ launch ============================================================
extern "C" void kernel_launch(void* const* d_in, const int* in_sizes, int n_in,
                              void* d_out, int out_size, void* d_ws, size_t ws_size,
                              hipStream_t stream)
{
    const float* feat = (const float*)d_in[0];
    const int*   knn  = (const int*)d_in[1];
    const float* dist = (const float*)d_in[2];
    const float* Wq   = (const float*)d_in[3];
    const float* Wk   = (const float*)d_in[4];
    const float* Wv   = (const float*)d_in[5];
    const float* Wo   = (const float*)d_in[6];
    const float* bo   = (const float*)d_in[7];
    const float* g1   = (const float*)d_in[8];
    const float* b1ln = (const float*)d_in[9];
    const float* W1   = (const float*)d_in[10];
    const float* b1f  = (const float*)d_in[11];
    const float* W2   = (const float*)d_in[12];
    const float* b2f  = (const float*)d_in[13];
    const float* g2   = (const float*)d_in[14];
    const float* b2ln = (const float*)d_in[15];
    float* out = (float*)d_out;

    const int n = in_sizes[0] / 128;
    const size_t ND = (size_t)n * 128;
    if (ws_size < 12 * ND + 262144) return;

    float* Q            = (float*)d_ws;                 // ND f32
    unsigned short* Kb  = (unsigned short*)(Q + ND);    // ND bf16
    unsigned short* Vb  = Kb + ND;                      // ND bf16
    float* att          = (float*)(Vb + ND);            // ND f32; becomes X in-place
    unsigned short* Wsz = (unsigned short*)(att + ND);  // 114688 bf16
    unsigned short* Hb  = (unsigned short*)Q;           // n*192 bf16, reuses dead Q

    k_prep<<<56, 256, 0, stream>>>(Wq, Wk, Wv, Wo, W1, W2, Wsz);
    k_qkv <<<(n + 63) / 64,   256, 0, stream>>>(feat, Wsz, Q, Kb, Vb, n);
    k_attn<<<(n + 3) / 4,     256, 0, stream>>>(Q, Kb, Vb, knn, dist, att, n);
    k_woln<<<(n + 127) / 128, 256, 0, stream>>>(att, Wsz, bo, feat, g1, b1ln, att, n);
    k_ffn1<<<(n + 127) / 128, 256, 0, stream>>>(att, Wsz, b1f, Hb, n);
    k_ffn2<<<(n + 127) / 128, 256, 0, stream>>>(Hb, att, Wsz, b2f, g2, b2ln, out, n);
}

// Round 4
// 198.192 us; speedup vs baseline: 21.9956x; 1.5471x over previous
//
#include <hip/hip_runtime.h>
#include <cmath>

typedef __attribute__((ext_vector_type(8))) short bf16x8;
typedef __attribute__((ext_vector_type(4))) float f32x4;

__device__ __forceinline__ unsigned short f2bf(float x) {
    unsigned int u = __float_as_uint(x);
    u += 0x7fffu + ((u >> 16) & 1u);
    return (unsigned short)(u >> 16);
}
__device__ __forceinline__ unsigned int pk2(float a, float b) {
    return (unsigned int)f2bf(a) | ((unsigned int)f2bf(b) << 16);
}
__device__ __forceinline__ float bflo(unsigned int u) { return __uint_as_float(u << 16); }
__device__ __forceinline__ float bfhi(unsigned int u) { return __uint_as_float(u & 0xffff0000u); }
__device__ __forceinline__ float gelu_exact(float v) {
    return 0.5f * v * (1.0f + erff(v * 0.70710678118654752440f));
}
__device__ __forceinline__ void unp16(const uint4& a, const uint4& b, float* q) {
    q[0]=bflo(a.x);  q[1]=bfhi(a.x);  q[2]=bflo(a.y);  q[3]=bfhi(a.y);
    q[4]=bflo(a.z);  q[5]=bfhi(a.z);  q[6]=bflo(a.w);  q[7]=bfhi(a.w);
    q[8]=bflo(b.x);  q[9]=bfhi(b.x);  q[10]=bflo(b.y); q[11]=bfhi(b.y);
    q[12]=bflo(b.z); q[13]=bfhi(b.z); q[14]=bflo(b.w); q[15]=bfhi(b.w);
}

// ============ K0: weight prep — fp32 -> bf16, MFMA fragment order ===============
// frag(ct,ks,l,j) = W[ks*32 + (l>>4)*8 + j][ct*16 + (l&15)]
// As A-operand this is A[m=ct*16+(l&15)][k] = W^T tile  (used as mfma 1st arg).
// shorts: Wq@0 Wk@16384 Wv@32768 Wo@49152 W1@65536 W2@90112 (total 114688)
__global__ __launch_bounds__(256, 1) void k_prep(
    const float* __restrict__ Wq, const float* __restrict__ Wk, const float* __restrict__ Wv,
    const float* __restrict__ Wo, const float* __restrict__ W1, const float* __restrict__ W2,
    unsigned short* __restrict__ wsz)
{
    int f = blockIdx.x * 256 + threadIdx.x;
    const float* W; unsigned short* dst; int M, KS, fl;
    if (f < 2048)       { W = Wq; dst = wsz;         M = 128; KS = 4; fl = f; }
    else if (f < 4096)  { W = Wk; dst = wsz + 16384; M = 128; KS = 4; fl = f - 2048; }
    else if (f < 6144)  { W = Wv; dst = wsz + 32768; M = 128; KS = 4; fl = f - 4096; }
    else if (f < 8192)  { W = Wo; dst = wsz + 49152; M = 128; KS = 4; fl = f - 6144; }
    else if (f < 11264) { W = W1; dst = wsz + 65536; M = 192; KS = 4; fl = f - 8192; }
    else if (f < 14336) { W = W2; dst = wsz + 90112; M = 128; KS = 6; fl = f - 11264; }
    else return;
    const int l  = fl & 63;
    const int ks = (fl >> 6) % KS;
    const int ct = (fl >> 6) / KS;
    const int k0 = ks * 32 + (l >> 4) * 8;
    const int col = ct * 16 + (l & 15);
    unsigned short tmp[8];
    #pragma unroll
    for (int j = 0; j < 8; ++j) tmp[j] = f2bf(W[(size_t)(k0 + j) * M + col]);
    ((uint4*)dst)[fl] = *(uint4*)tmp;
}

// ============ K1: QKV projection. 512 thr, 128 rows/block, 1 weight in LDS ======
// Transposed mfma: D[outcol][node]; lane owns node=w*16+(lane&15), 4 cols per ct.
__global__ __launch_bounds__(512, 1) void k_qkv(
    const float* __restrict__ feat, const unsigned short* __restrict__ wsz,
    unsigned short* __restrict__ Qb, unsigned short* __restrict__ Kb,
    unsigned short* __restrict__ Vb, int n)
{
    __shared__ __align__(16) unsigned short wld[16384];     // 32 KB
    __shared__ __align__(16) unsigned short at[128 * 136];  // 34.8 KB
    const int tid = threadIdx.x;
    const int row0 = blockIdx.x * 128;

    for (int i = tid; i < 4096; i += 512) {                 // 128 rows x 32 float4
        int row = i >> 5, col = (i & 31) * 4;
        float4 v = make_float4(0.f, 0.f, 0.f, 0.f);
        int gr = row0 + row;
        if (gr < n) v = ((const float4*)(feat + (size_t)gr * 128))[i & 31];
        *((uint2*)&at[row * 136 + col]) = make_uint2(pk2(v.x, v.y), pk2(v.z, v.w));
    }

    const int w = tid >> 6, lane = tid & 63;
    const int lrow = lane & 15, kgrp = lane >> 4;
    const int node = row0 + w * 16 + lrow;
    bf16x8 bfr[4];

    for (int mat = 0; mat < 3; ++mat) {
        for (int i = tid; i < 2048; i += 512)
            ((uint4*)wld)[i] = ((const uint4*)(wsz + mat * 16384))[i];
        __syncthreads();
        if (mat == 0) {
            #pragma unroll
            for (int ks = 0; ks < 4; ++ks)
                bfr[ks] = *(const bf16x8*)&at[(w * 16 + lrow) * 136 + ks * 32 + kgrp * 8];
        }
        f32x4 acc[8];
        #pragma unroll
        for (int ct = 0; ct < 8; ++ct) acc[ct] = (f32x4){0.f, 0.f, 0.f, 0.f};
        #pragma unroll
        for (int ct = 0; ct < 8; ++ct)
            #pragma unroll
            for (int ks = 0; ks < 4; ++ks) {
                bf16x8 afr = *(const bf16x8*)&wld[((ct * 4 + ks) * 64 + lane) * 8];
                acc[ct] = __builtin_amdgcn_mfma_f32_16x16x32_bf16(afr, bfr[ks], acc[ct], 0, 0, 0);
            }
        unsigned short* O = (mat == 0) ? Qb : (mat == 1 ? Kb : Vb);
        if (node < n) {
            #pragma unroll
            for (int ct = 0; ct < 8; ++ct) {
                int col = ct * 16 + kgrp * 4;
                *((uint2*)(O + (size_t)node * 128 + col)) =
                    make_uint2(pk2(acc[ct][0], acc[ct][1]), pk2(acc[ct][2], acc[ct][3]));
            }
        }
        __syncthreads();
    }
}

// ============ K2: KNN attention, all-bf16 gather, V hoisted ====================
__global__ __launch_bounds__(256, 1) void k_attn(
    const unsigned short* __restrict__ Qb, const unsigned short* __restrict__ Kb,
    const unsigned short* __restrict__ Vb,
    const int* __restrict__ knn, const float* __restrict__ dist,
    unsigned short* __restrict__ attb, int n)
{
    const int lane = threadIdx.x & 63;
    const int node = blockIdx.x * 4 + (threadIdx.x >> 6);
    if (node >= n) return;
    const int h = lane >> 3, r = lane & 7;

    const unsigned short* qp = Qb + (size_t)node * 128 + h * 16;
    uint4 qa = *(const uint4*)qp;
    uint4 qb = *(const uint4*)(qp + 8);
    float q[16];
    unp16(qa, qb, q);
    const float hs = exp2f(-(float)(h + 1));

    int idx[4]; float sd[4];
    #pragma unroll
    for (int jj = 0; jj < 4; ++jj) {
        int j = r + jj * 8;
        idx[jj] = knn[(size_t)node * 32 + j];
        sd[jj]  = dist[(size_t)node * 32 + j] * hs;
    }

    // issue all K and V loads up front (16 uint4 in flight per lane)
    uint4 k0[4], k1[4], v0[4], v1[4];
    #pragma unroll
    for (int jj = 0; jj < 4; ++jj) {
        const unsigned short* kp = Kb + (size_t)idx[jj] * 128 + h * 16;
        k0[jj] = *(const uint4*)kp;
        k1[jj] = *(const uint4*)(kp + 8);
    }
    #pragma unroll
    for (int jj = 0; jj < 4; ++jj) {
        const unsigned short* vp = Vb + (size_t)idx[jj] * 128 + h * 16;
        v0[jj] = *(const uint4*)vp;
        v1[jj] = *(const uint4*)(vp + 8);
    }

    float ap[4], an[4];
    #pragma unroll
    for (int jj = 0; jj < 4; ++jj) {
        float kv[16];
        unp16(k0[jj], k1[jj], kv);
        float s = 0.f;
        #pragma unroll
        for (int i = 0; i < 16; ++i) s = fmaf(q[i], kv[i], s);
        float raw = s * 0.25f;
        ap[jj] = raw - sd[jj];
        an[jj] = (-raw - sd[jj]) * (1.0f / 0.6f);
    }

    float mp = fmaxf(fmaxf(ap[0], ap[1]), fmaxf(ap[2], ap[3]));
    float mn = fmaxf(fmaxf(an[0], an[1]), fmaxf(an[2], an[3]));
    #pragma unroll
    for (int msk = 1; msk < 8; msk <<= 1) {
        mp = fmaxf(mp, __shfl_xor(mp, msk, 8));
        mn = fmaxf(mn, __shfl_xor(mn, msk, 8));
    }
    float ep[4], en[4], sp = 0.f, sn = 0.f;
    #pragma unroll
    for (int jj = 0; jj < 4; ++jj) {
        ep[jj] = expf(ap[jj] - mp); sp += ep[jj];
        en[jj] = expf(an[jj] - mn); sn += en[jj];
    }
    #pragma unroll
    for (int msk = 1; msk < 8; msk <<= 1) {
        sp += __shfl_xor(sp, msk, 8);
        sn += __shfl_xor(sn, msk, 8);
    }
    const float isp = 1.0f / sp;
    const float isn = 1.5f / sn;

    float acc[16];
    #pragma unroll
    for (int i = 0; i < 16; ++i) acc[i] = 0.f;
    #pragma unroll
    for (int jj = 0; jj < 4; ++jj) {
        float wgt = ep[jj] * isp - en[jj] * isn;
        float vv[16];
        unp16(v0[jj], v1[jj], vv);
        #pragma unroll
        for (int i = 0; i < 16; ++i) acc[i] = fmaf(wgt, vv[i], acc[i]);
    }
    #pragma unroll
    for (int i = 0; i < 16; ++i) {
        #pragma unroll
        for (int msk = 1; msk < 8; msk <<= 1) acc[i] += __shfl_xor(acc[i], msk, 8);
    }
    if (r == 0) {
        unsigned int o[8];
        #pragma unroll
        for (int i = 0; i < 8; ++i) o[i] = pk2(acc[2 * i], acc[2 * i + 1]);
        unsigned short* op = attb + (size_t)node * 128 + h * 16;
        *((uint4*)op)     = make_uint4(o[0], o[1], o[2], o[3]);
        *((uint4*)(op+8)) = make_uint4(o[4], o[5], o[6], o[7]);
    }
}

// ============ K3: fused tail: X=LN1(att@Wo+bo+feat); H=gelu(X@W1+b1);
//              out=LN2(H@W2+b2+X). Persistent; weights staged once. ==============
__global__ __launch_bounds__(256, 1) void k_tail(
    const unsigned short* __restrict__ attb, const float* __restrict__ feat,
    const unsigned short* __restrict__ wsz,
    const float* __restrict__ bo, const float* __restrict__ g1, const float* __restrict__ b1ln,
    const float* __restrict__ b1f, const float* __restrict__ b2f,
    const float* __restrict__ g2, const float* __restrict__ b2ln,
    float* __restrict__ out, int n, int tiles)
{
    __shared__ __align__(16) unsigned short wo_s[16384];   // 32 KB
    __shared__ __align__(16) unsigned short w1_s[24576];   // 48 KB
    __shared__ __align__(16) unsigned short w2_s[24576];   // 48 KB
    __shared__ __align__(16) unsigned short act[64 * 200]; // 25.6 KB
    const int tid = threadIdx.x;

    for (int i = tid; i < 2048; i += 256) ((uint4*)wo_s)[i] = ((const uint4*)(wsz + 49152))[i];
    for (int i = tid; i < 3072; i += 256) ((uint4*)w1_s)[i] = ((const uint4*)(wsz + 65536))[i];
    for (int i = tid; i < 3072; i += 256) ((uint4*)w2_s)[i] = ((const uint4*)(wsz + 90112))[i];

    const int w = tid >> 6, lane = tid & 63;
    const int lrow = lane & 15, kgrp = lane >> 4;
    const int lbase = (w * 16 + lrow) * 200;

    for (int t = blockIdx.x; t < tiles; t += gridDim.x) {
        const int row0 = t * 64;
        const int node = row0 + w * 16 + lrow;
        const bool valid = node < n;
        __syncthreads();                                   // act safe to overwrite
        for (int i = tid; i < 1024; i += 256) {            // 64 rows x 16 uint4
            int row = i >> 4, cg = i & 15;
            int gr = row0 + row;
            uint4 v = make_uint4(0u, 0u, 0u, 0u);
            if (gr < n) v = *(const uint4*)(attb + (size_t)gr * 128 + cg * 8);
            *((uint4*)&act[row * 200 + cg * 8]) = v;
        }
        __syncthreads();

        // ---- GEMM1: X = att@Wo + bo + feat ----
        bf16x8 bfr[6];
        #pragma unroll
        for (int ks = 0; ks < 4; ++ks)
            bfr[ks] = *(const bf16x8*)&act[lbase + ks * 32 + kgrp * 8];
        f32x4 X[8];
        #pragma unroll
        for (int ct = 0; ct < 8; ++ct) {
            X[ct] = (f32x4){0.f, 0.f, 0.f, 0.f};
            #pragma unroll
            for (int ks = 0; ks < 4; ++ks) {
                bf16x8 afr = *(const bf16x8*)&wo_s[((ct * 4 + ks) * 64 + lane) * 8];
                X[ct] = __builtin_amdgcn_mfma_f32_16x16x32_bf16(afr, bfr[ks], X[ct], 0, 0, 0);
            }
        }
        #pragma unroll
        for (int ct = 0; ct < 8; ++ct) {
            int col = ct * 16 + kgrp * 4;
            float4 bv = *((const float4*)(bo + col));
            float4 fr = make_float4(0.f, 0.f, 0.f, 0.f);
            if (valid) fr = *((const float4*)(feat + (size_t)node * 128 + col));
            X[ct][0] += bv.x + fr.x; X[ct][1] += bv.y + fr.y;
            X[ct][2] += bv.z + fr.z; X[ct][3] += bv.w + fr.w;
        }
        // LN1 (row = node, 32 in-lane values + lanes {l, l^16, l^32, l^48})
        float s = 0.f;
        #pragma unroll
        for (int ct = 0; ct < 8; ++ct) s += X[ct][0] + X[ct][1] + X[ct][2] + X[ct][3];
        s += __shfl_xor(s, 16); s += __shfl_xor(s, 32);
        const float mu1 = s * (1.0f / 128.0f);
        float s2 = 0.f;
        #pragma unroll
        for (int ct = 0; ct < 8; ++ct)
            #pragma unroll
            for (int rr = 0; rr < 4; ++rr) { float d = X[ct][rr] - mu1; s2 = fmaf(d, d, s2); }
        s2 += __shfl_xor(s2, 16); s2 += __shfl_xor(s2, 32);
        const float rs1 = rsqrtf(s2 * (1.0f / 128.0f) + 1e-5f);
        f32x4 XN[8];
        #pragma unroll
        for (int ct = 0; ct < 8; ++ct) {
            int col = ct * 16 + kgrp * 4;
            float4 gg = *((const float4*)(g1 + col));
            float4 bb = *((const float4*)(b1ln + col));
            XN[ct][0] = (X[ct][0] - mu1) * rs1 * gg.x + bb.x;
            XN[ct][1] = (X[ct][1] - mu1) * rs1 * gg.y + bb.y;
            XN[ct][2] = (X[ct][2] - mu1) * rs1 * gg.z + bb.z;
            XN[ct][3] = (X[ct][3] - mu1) * rs1 * gg.w + bb.w;
        }
        __syncthreads();                                   // done reading att frags
        #pragma unroll
        for (int ct = 0; ct < 8; ++ct) {
            int col = ct * 16 + kgrp * 4;
            *((uint2*)&act[lbase + col]) =
                make_uint2(pk2(XN[ct][0], XN[ct][1]), pk2(XN[ct][2], XN[ct][3]));
        }
        __syncthreads();

        // ---- GEMM2: H = gelu(X@W1 + b1) ----
        #pragma unroll
        for (int ks = 0; ks < 4; ++ks)
            bfr[ks] = *(const bf16x8*)&act[lbase + ks * 32 + kgrp * 8];
        f32x4 Hc[12];
        #pragma unroll
        for (int ct = 0; ct < 12; ++ct) {
            Hc[ct] = (f32x4){0.f, 0.f, 0.f, 0.f};
            #pragma unroll
            for (int ks = 0; ks < 4; ++ks) {
                bf16x8 afr = *(const bf16x8*)&w1_s[((ct * 4 + ks) * 64 + lane) * 8];
                Hc[ct] = __builtin_amdgcn_mfma_f32_16x16x32_bf16(afr, bfr[ks], Hc[ct], 0, 0, 0);
            }
        }
        #pragma unroll
        for (int ct = 0; ct < 12; ++ct) {
            int col = ct * 16 + kgrp * 4;
            float4 bv = *((const float4*)(b1f + col));
            Hc[ct][0] = gelu_exact(Hc[ct][0] + bv.x);
            Hc[ct][1] = gelu_exact(Hc[ct][1] + bv.y);
            Hc[ct][2] = gelu_exact(Hc[ct][2] + bv.z);
            Hc[ct][3] = gelu_exact(Hc[ct][3] + bv.w);
        }
        __syncthreads();                                   // done reading X frags
        #pragma unroll
        for (int ct = 0; ct < 12; ++ct) {
            int col = ct * 16 + kgrp * 4;
            *((uint2*)&act[lbase + col]) =
                make_uint2(pk2(Hc[ct][0], Hc[ct][1]), pk2(Hc[ct][2], Hc[ct][3]));
        }
        __syncthreads();

        // ---- GEMM3: Y = H@W2 + b2 + X; LN2 ----
        #pragma unroll
        for (int ks = 0; ks < 6; ++ks)
            bfr[ks] = *(const bf16x8*)&act[lbase + ks * 32 + kgrp * 8];
        f32x4 Y[8];
        #pragma unroll
        for (int ct = 0; ct < 8; ++ct) {
            Y[ct] = (f32x4){0.f, 0.f, 0.f, 0.f};
            #pragma unroll
            for (int ks = 0; ks < 6; ++ks) {
                bf16x8 afr = *(const bf16x8*)&w2_s[((ct * 6 + ks) * 64 + lane) * 8];
                Y[ct] = __builtin_amdgcn_mfma_f32_16x16x32_bf16(afr, bfr[ks], Y[ct], 0, 0, 0);
            }
        }
        #pragma unroll
        for (int ct = 0; ct < 8; ++ct) {
            int col = ct * 16 + kgrp * 4;
            float4 bv = *((const float4*)(b2f + col));
            Y[ct][0] += bv.x + XN[ct][0]; Y[ct][1] += bv.y + XN[ct][1];
            Y[ct][2] += bv.z + XN[ct][2]; Y[ct][3] += bv.w + XN[ct][3];
        }
        float t1 = 0.f;
        #pragma unroll
        for (int ct = 0; ct < 8; ++ct) t1 += Y[ct][0] + Y[ct][1] + Y[ct][2] + Y[ct][3];
        t1 += __shfl_xor(t1, 16); t1 += __shfl_xor(t1, 32);
        const float mu2 = t1 * (1.0f / 128.0f);
        float t2 = 0.f;
        #pragma unroll
        for (int ct = 0; ct < 8; ++ct)
            #pragma unroll
            for (int rr = 0; rr < 4; ++rr) { float d = Y[ct][rr] - mu2; t2 = fmaf(d, d, t2); }
        t2 += __shfl_xor(t2, 16); t2 += __shfl_xor(t2, 32);
        const float rs2 = rsqrtf(t2 * (1.0f / 128.0f) + 1e-5f);
        if (valid) {
            #pragma unroll
            for (int ct = 0; ct < 8; ++ct) {
                int col = ct * 16 + kgrp * 4;
                float4 gg = *((const float4*)(g2 + col));
                float4 bb = *((const float4*)(b2ln + col));
                float4 o;
                o.x = (Y[ct][0] - mu2) * rs2 * gg.x + bb.x;
                o.y = (Y[ct][1] - mu2) * rs2 * gg.y + bb.y;
                o.z = (Y[ct][2] - mu2) * rs2 * gg.z + bb.z;
                o.w = (Y[ct][3] - mu2) * rs2 * gg.w + bb.w;
                *((float4*)(out + (size_t)node * 128 + col)) = o;
            }
        }
    }
}

// ============ launch ============================================================
extern "C" void kernel_launch(void* const* d_in, const int* in_sizes, int n_in,
                              void* d_out, int out_size, void* d_ws, size_t ws_size,
                              hipStream_t stream)
{
    const float* feat = (const float*)d_in[0];
    const int*   knn  = (const int*)d_in[1];
    const float* dist = (const float*)d_in[2];
    const float* Wq   = (const float*)d_in[3];
    const float* Wk   = (const float*)d_in[4];
    const float* Wv   = (const float*)d_in[5];
    const float* Wo   = (const float*)d_in[6];
    const float* bo   = (const float*)d_in[7];
    const float* g1   = (const float*)d_in[8];
    const float* b1ln = (const float*)d_in[9];
    const float* W1   = (const float*)d_in[10];
    const float* b1f  = (const float*)d_in[11];
    const float* W2   = (const float*)d_in[12];
    const float* b2f  = (const float*)d_in[13];
    const float* g2   = (const float*)d_in[14];
    const float* b2ln = (const float*)d_in[15];
    float* out = (float*)d_out;

    const int n = in_sizes[0] / 128;
    const size_t ND = (size_t)n * 128;
    if (ws_size < 8 * ND + 262144) return;

    unsigned short* Qb   = (unsigned short*)d_ws;     // ND bf16
    unsigned short* Kb   = Qb + ND;                   // ND bf16
    unsigned short* Vb   = Kb + ND;                   // ND bf16
    unsigned short* attb = Vb + ND;                   // ND bf16
    unsigned short* Wsz  = attb + ND;                 // 114688 bf16

    const int tiles64 = (n + 63) / 64;
    k_prep<<<56, 256, 0, stream>>>(Wq, Wk, Wv, Wo, W1, W2, Wsz);
    k_qkv <<<(n + 127) / 128, 512, 0, stream>>>(feat, Wsz, Qb, Kb, Vb, n);
    k_attn<<<(n + 3) / 4, 256, 0, stream>>>(Qb, Kb, Vb, knn, dist, attb, n);
    k_tail<<<256, 256, 0, stream>>>(attb, feat, Wsz, bo, g1, b1ln, b1f, b2f, g2, b2ln,
                                    out, n, tiles64);
}

// Round 5
// 191.007 us; speedup vs baseline: 22.8230x; 1.0376x over previous
//
#include <hip/hip_runtime.h>
#include <hip/hip_fp16.h>
#include <cmath>

typedef __attribute__((ext_vector_type(8))) _Float16 f16x8;
typedef __attribute__((ext_vector_type(4))) float f32x4;

__device__ __forceinline__ unsigned int pkh(float a, float b) {
    __half2 h = __floats2half2_rn(a, b);
    return *(unsigned int*)&h;
}
__device__ __forceinline__ float gelu_exact(float v) {
    return 0.5f * v * (1.0f + erff(v * 0.70710678118654752440f));
}
__device__ __forceinline__ __half2 shfl8h(__half2 x, int m) {
    int xi = *(int*)&x;
    int yi = __shfl_xor(xi, m, 8);
    return *(__half2*)&yi;
}

// ============ K0: weight prep — fp32 -> fp16, MFMA A-fragment order =============
// frag(ct,ks,l,j) = W[ks*32 + (l>>4)*8 + j][ct*16 + (l&15)]  (A-operand = W^T tile)
// shorts: Wq@0 Wk@16384 Wv@32768 Wo@49152 W1@65536 W2@90112 (total 114688)
__global__ __launch_bounds__(256, 1) void k_prep(
    const float* __restrict__ Wq, const float* __restrict__ Wk, const float* __restrict__ Wv,
    const float* __restrict__ Wo, const float* __restrict__ W1, const float* __restrict__ W2,
    unsigned short* __restrict__ wsz)
{
    int f = blockIdx.x * 256 + threadIdx.x;
    const float* W; unsigned short* dst; int M, KS, fl;
    if (f < 2048)       { W = Wq; dst = wsz;         M = 128; KS = 4; fl = f; }
    else if (f < 4096)  { W = Wk; dst = wsz + 16384; M = 128; KS = 4; fl = f - 2048; }
    else if (f < 6144)  { W = Wv; dst = wsz + 32768; M = 128; KS = 4; fl = f - 4096; }
    else if (f < 8192)  { W = Wo; dst = wsz + 49152; M = 128; KS = 4; fl = f - 6144; }
    else if (f < 11264) { W = W1; dst = wsz + 65536; M = 192; KS = 4; fl = f - 8192; }
    else if (f < 14336) { W = W2; dst = wsz + 90112; M = 128; KS = 6; fl = f - 11264; }
    else return;
    const int l  = fl & 63;
    const int ks = (fl >> 6) % KS;
    const int ct = (fl >> 6) / KS;
    const int k0 = ks * 32 + (l >> 4) * 8;
    const int col = ct * 16 + (l & 15);
    unsigned short tmp[8];
    #pragma unroll
    for (int j = 0; j < 8; ++j) {
        __half hh = __float2half(W[(size_t)(k0 + j) * M + col]);
        tmp[j] = *(unsigned short*)&hh;
    }
    ((uint4*)dst)[fl] = *(uint4*)tmp;
}

// ============ K1: QKV projection — no LDS, frags straight from global ===========
// 256 thr = 4 waves x 16 rows; weights L1/L2-hot; feat rows read once.
__global__ __launch_bounds__(256, 4) void k_qkv(
    const float* __restrict__ feat, const unsigned short* __restrict__ wsz,
    unsigned short* __restrict__ Qb, unsigned short* __restrict__ Kb,
    unsigned short* __restrict__ Vb, int n)
{
    const int w = threadIdx.x >> 6, lane = threadIdx.x & 63;
    const int lrow = lane & 15, kgrp = lane >> 4;
    const int node = blockIdx.x * 64 + w * 16 + lrow;
    const bool valid = node < n;

    f16x8 bfr[4];
    #pragma unroll
    for (int ks = 0; ks < 4; ++ks) {
        float4 lo = make_float4(0.f, 0.f, 0.f, 0.f), hi = lo;
        if (valid) {
            const float* p = feat + (size_t)node * 128 + ks * 32 + kgrp * 8;
            lo = *(const float4*)p;
            hi = *(const float4*)(p + 4);
        }
        f16x8 b;
        b[0] = (_Float16)lo.x; b[1] = (_Float16)lo.y; b[2] = (_Float16)lo.z; b[3] = (_Float16)lo.w;
        b[4] = (_Float16)hi.x; b[5] = (_Float16)hi.y; b[6] = (_Float16)hi.z; b[7] = (_Float16)hi.w;
        bfr[ks] = b;
    }

    for (int mat = 0; mat < 3; ++mat) {
        const unsigned short* wb = wsz + mat * 16384;
        f32x4 acc[8];
        #pragma unroll
        for (int ct = 0; ct < 8; ++ct) acc[ct] = (f32x4){0.f, 0.f, 0.f, 0.f};
        #pragma unroll
        for (int ct = 0; ct < 8; ++ct)
            #pragma unroll
            for (int ks = 0; ks < 4; ++ks) {
                f16x8 afr = *(const f16x8*)(wb + ((size_t)(ct * 4 + ks) * 64 + lane) * 8);
                acc[ct] = __builtin_amdgcn_mfma_f32_16x16x32_f16(afr, bfr[ks], acc[ct], 0, 0, 0);
            }
        unsigned short* O = (mat == 0) ? Qb : (mat == 1 ? Kb : Vb);
        if (valid) {
            #pragma unroll
            for (int ct = 0; ct < 8; ++ct) {
                int col = ct * 16 + kgrp * 4;
                *((uint2*)(O + (size_t)node * 128 + col)) =
                    make_uint2(pkh(acc[ct][0], acc[ct][1]), pkh(acc[ct][2], acc[ct][3]));
            }
        }
    }
}

// ============ K2: KNN attention — fp16 gather, hfma2 math, full load hoist ======
__global__ __launch_bounds__(256, 4) void k_attn(
    const unsigned short* __restrict__ Qb, const unsigned short* __restrict__ Kb,
    const unsigned short* __restrict__ Vb,
    const int* __restrict__ knn, const float* __restrict__ dist,
    unsigned short* __restrict__ attb, int n)
{
    const int lane = threadIdx.x & 63;
    const int node = blockIdx.x * 4 + (threadIdx.x >> 6);
    if (node >= n) return;
    const int h = lane >> 3, r = lane & 7;
    const float hs = exp2f(-(float)(h + 1));

    int idx[4]; float sd[4];
    #pragma unroll
    for (int jj = 0; jj < 4; ++jj) {
        int j = r + jj * 8;
        idx[jj] = knn[(size_t)node * 32 + j];
        sd[jj]  = dist[(size_t)node * 32 + j] * hs;
    }

    const unsigned short* qp = Qb + (size_t)node * 128 + h * 16;
    __half2 q2[8];
    *((uint4*)&q2[0]) = *(const uint4*)qp;
    *((uint4*)&q2[4]) = *(const uint4*)(qp + 8);

    // all 16 gather loads issued up front (launch_bounds gives VGPR room)
    uint4 k0[4], k1[4], v0[4], v1[4];
    #pragma unroll
    for (int jj = 0; jj < 4; ++jj) {
        const unsigned short* kp = Kb + (size_t)idx[jj] * 128 + h * 16;
        k0[jj] = *(const uint4*)kp;
        k1[jj] = *(const uint4*)(kp + 8);
    }
    #pragma unroll
    for (int jj = 0; jj < 4; ++jj) {
        const unsigned short* vp = Vb + (size_t)idx[jj] * 128 + h * 16;
        v0[jj] = *(const uint4*)vp;
        v1[jj] = *(const uint4*)(vp + 8);
    }

    float ap[4], an[4];
    #pragma unroll
    for (int jj = 0; jj < 4; ++jj) {
        const __half2* ka = (const __half2*)&k0[jj];
        const __half2* kb = (const __half2*)&k1[jj];
        __half2 s0 = __hmul2(q2[0], ka[0]);
        s0 = __hfma2(q2[1], ka[1], s0);
        s0 = __hfma2(q2[2], ka[2], s0);
        s0 = __hfma2(q2[3], ka[3], s0);
        __half2 s1 = __hmul2(q2[4], kb[0]);
        s1 = __hfma2(q2[5], kb[1], s1);
        s1 = __hfma2(q2[6], kb[2], s1);
        s1 = __hfma2(q2[7], kb[3], s1);
        float s = __low2float(s0) + __high2float(s0) + __low2float(s1) + __high2float(s1);
        float raw = s * 0.25f;
        ap[jj] = raw - sd[jj];
        an[jj] = (-raw - sd[jj]) * (1.0f / 0.6f);
    }

    float mp = fmaxf(fmaxf(ap[0], ap[1]), fmaxf(ap[2], ap[3]));
    float mn = fmaxf(fmaxf(an[0], an[1]), fmaxf(an[2], an[3]));
    #pragma unroll
    for (int msk = 1; msk < 8; msk <<= 1) {
        mp = fmaxf(mp, __shfl_xor(mp, msk, 8));
        mn = fmaxf(mn, __shfl_xor(mn, msk, 8));
    }
    float ep[4], en[4], sp = 0.f, sn = 0.f;
    #pragma unroll
    for (int jj = 0; jj < 4; ++jj) {
        ep[jj] = expf(ap[jj] - mp); sp += ep[jj];
        en[jj] = expf(an[jj] - mn); sn += en[jj];
    }
    #pragma unroll
    for (int msk = 1; msk < 8; msk <<= 1) {
        sp += __shfl_xor(sp, msk, 8);
        sn += __shfl_xor(sn, msk, 8);
    }
    const float isp = 1.0f / sp;
    const float isn = 1.5f / sn;

    __half2 acc2[8];
    #pragma unroll
    for (int i = 0; i < 8; ++i) acc2[i] = __float2half2_rn(0.f);
    #pragma unroll
    for (int jj = 0; jj < 4; ++jj) {
        float wgt = ep[jj] * isp - en[jj] * isn;
        __half2 w2 = __float2half2_rn(wgt);
        const __half2* va = (const __half2*)&v0[jj];
        const __half2* vb = (const __half2*)&v1[jj];
        acc2[0] = __hfma2(w2, va[0], acc2[0]);
        acc2[1] = __hfma2(w2, va[1], acc2[1]);
        acc2[2] = __hfma2(w2, va[2], acc2[2]);
        acc2[3] = __hfma2(w2, va[3], acc2[3]);
        acc2[4] = __hfma2(w2, vb[0], acc2[4]);
        acc2[5] = __hfma2(w2, vb[1], acc2[5]);
        acc2[6] = __hfma2(w2, vb[2], acc2[6]);
        acc2[7] = __hfma2(w2, vb[3], acc2[7]);
    }
    #pragma unroll
    for (int i = 0; i < 8; ++i) {
        acc2[i] = __hadd2(acc2[i], shfl8h(acc2[i], 1));
        acc2[i] = __hadd2(acc2[i], shfl8h(acc2[i], 2));
        acc2[i] = __hadd2(acc2[i], shfl8h(acc2[i], 4));
    }
    if (r == 0) {
        unsigned short* op = attb + (size_t)node * 128 + h * 16;
        *((uint4*)op)       = *(uint4*)&acc2[0];
        *((uint4*)(op + 8)) = *(uint4*)&acc2[4];
    }
}

// ============ K3: X = LN1(att@Wo + bo + feat) -> fp16 ws ========================
__global__ __launch_bounds__(512, 1) void k_tail1(
    const unsigned short* __restrict__ attb, const float* __restrict__ feat,
    const unsigned short* __restrict__ wsz,
    const float* __restrict__ bo, const float* __restrict__ g1, const float* __restrict__ b1ln,
    unsigned short* __restrict__ Xb, int n)
{
    __shared__ __align__(16) unsigned short wo_s[16384];      // 32 KB
    const int tid = threadIdx.x;
    for (int i = tid; i < 2048; i += 512)
        ((uint4*)wo_s)[i] = ((const uint4*)(wsz + 49152))[i];

    const int w = tid >> 6, lane = tid & 63;
    const int lrow = lane & 15, kgrp = lane >> 4;
    const int node = blockIdx.x * 128 + w * 16 + lrow;
    const bool valid = node < n;

    f16x8 bfr[4];
    #pragma unroll
    for (int ks = 0; ks < 4; ++ks) {
        uint4 u = make_uint4(0u, 0u, 0u, 0u);
        if (valid) u = *(const uint4*)(attb + (size_t)node * 128 + ks * 32 + kgrp * 8);
        bfr[ks] = *(f16x8*)&u;
    }
    __syncthreads();

    f32x4 X[8];
    #pragma unroll
    for (int ct = 0; ct < 8; ++ct) {
        X[ct] = (f32x4){0.f, 0.f, 0.f, 0.f};
        #pragma unroll
        for (int ks = 0; ks < 4; ++ks) {
            f16x8 afr = *(const f16x8*)&wo_s[((ct * 4 + ks) * 64 + lane) * 8];
            X[ct] = __builtin_amdgcn_mfma_f32_16x16x32_f16(afr, bfr[ks], X[ct], 0, 0, 0);
        }
    }
    #pragma unroll
    for (int ct = 0; ct < 8; ++ct) {
        int col = ct * 16 + kgrp * 4;
        float4 bv = *((const float4*)(bo + col));
        float4 fr = make_float4(0.f, 0.f, 0.f, 0.f);
        if (valid) fr = *((const float4*)(feat + (size_t)node * 128 + col));
        X[ct][0] += bv.x + fr.x; X[ct][1] += bv.y + fr.y;
        X[ct][2] += bv.z + fr.z; X[ct][3] += bv.w + fr.w;
    }
    float s = 0.f;
    #pragma unroll
    for (int ct = 0; ct < 8; ++ct) s += X[ct][0] + X[ct][1] + X[ct][2] + X[ct][3];
    s += __shfl_xor(s, 16); s += __shfl_xor(s, 32);
    const float mu = s * (1.0f / 128.0f);
    float s2 = 0.f;
    #pragma unroll
    for (int ct = 0; ct < 8; ++ct)
        #pragma unroll
        for (int rr = 0; rr < 4; ++rr) { float d = X[ct][rr] - mu; s2 = fmaf(d, d, s2); }
    s2 += __shfl_xor(s2, 16); s2 += __shfl_xor(s2, 32);
    const float rs = rsqrtf(s2 * (1.0f / 128.0f) + 1e-5f);
    if (valid) {
        #pragma unroll
        for (int ct = 0; ct < 8; ++ct) {
            int col = ct * 16 + kgrp * 4;
            float4 gg = *((const float4*)(g1 + col));
            float4 bb = *((const float4*)(b1ln + col));
            float x0 = (X[ct][0] - mu) * rs * gg.x + bb.x;
            float x1 = (X[ct][1] - mu) * rs * gg.y + bb.y;
            float x2 = (X[ct][2] - mu) * rs * gg.z + bb.z;
            float x3 = (X[ct][3] - mu) * rs * gg.w + bb.w;
            *((uint2*)(Xb + (size_t)node * 128 + col)) = make_uint2(pkh(x0, x1), pkh(x2, x3));
        }
    }
}

// ============ K4: H = gelu(X@W1 + b1) -> fp16 ws ================================
__global__ __launch_bounds__(512, 1) void k_ffn1(
    const unsigned short* __restrict__ Xb, const unsigned short* __restrict__ wsz,
    const float* __restrict__ b1f, unsigned short* __restrict__ Hb, int n)
{
    __shared__ __align__(16) unsigned short w1_s[24576];      // 48 KB
    const int tid = threadIdx.x;
    for (int i = tid; i < 3072; i += 512)
        ((uint4*)w1_s)[i] = ((const uint4*)(wsz + 65536))[i];

    const int w = tid >> 6, lane = tid & 63;
    const int lrow = lane & 15, kgrp = lane >> 4;
    const int node = blockIdx.x * 128 + w * 16 + lrow;
    const bool valid = node < n;

    f16x8 bfr[4];
    #pragma unroll
    for (int ks = 0; ks < 4; ++ks) {
        uint4 u = make_uint4(0u, 0u, 0u, 0u);
        if (valid) u = *(const uint4*)(Xb + (size_t)node * 128 + ks * 32 + kgrp * 8);
        bfr[ks] = *(f16x8*)&u;
    }
    __syncthreads();

    f32x4 acc[12];
    #pragma unroll
    for (int ct = 0; ct < 12; ++ct) {
        acc[ct] = (f32x4){0.f, 0.f, 0.f, 0.f};
        #pragma unroll
        for (int ks = 0; ks < 4; ++ks) {
            f16x8 afr = *(const f16x8*)&w1_s[((ct * 4 + ks) * 64 + lane) * 8];
            acc[ct] = __builtin_amdgcn_mfma_f32_16x16x32_f16(afr, bfr[ks], acc[ct], 0, 0, 0);
        }
    }
    if (valid) {
        #pragma unroll
        for (int ct = 0; ct < 12; ++ct) {
            int col = ct * 16 + kgrp * 4;
            float4 bv = *((const float4*)(b1f + col));
            float h0 = gelu_exact(acc[ct][0] + bv.x);
            float h1 = gelu_exact(acc[ct][1] + bv.y);
            float h2 = gelu_exact(acc[ct][2] + bv.z);
            float h3 = gelu_exact(acc[ct][3] + bv.w);
            *((uint2*)(Hb + (size_t)node * 192 + col)) = make_uint2(pkh(h0, h1), pkh(h2, h3));
        }
    }
}

// ============ K5: out = LN2(H@W2 + b2 + X) ======================================
__global__ __launch_bounds__(512, 1) void k_ffn2(
    const unsigned short* __restrict__ Hb, const unsigned short* __restrict__ Xb,
    const unsigned short* __restrict__ wsz, const float* __restrict__ b2f,
    const float* __restrict__ g2, const float* __restrict__ b2ln,
    float* __restrict__ out, int n)
{
    __shared__ __align__(16) unsigned short w2_s[24576];      // 48 KB
    const int tid = threadIdx.x;
    for (int i = tid; i < 3072; i += 512)
        ((uint4*)w2_s)[i] = ((const uint4*)(wsz + 90112))[i];

    const int w = tid >> 6, lane = tid & 63;
    const int lrow = lane & 15, kgrp = lane >> 4;
    const int node = blockIdx.x * 128 + w * 16 + lrow;
    const bool valid = node < n;

    f16x8 bfr[6];
    #pragma unroll
    for (int ks = 0; ks < 6; ++ks) {
        uint4 u = make_uint4(0u, 0u, 0u, 0u);
        if (valid) u = *(const uint4*)(Hb + (size_t)node * 192 + ks * 32 + kgrp * 8);
        bfr[ks] = *(f16x8*)&u;
    }
    __syncthreads();

    f32x4 Y[8];
    #pragma unroll
    for (int ct = 0; ct < 8; ++ct) {
        Y[ct] = (f32x4){0.f, 0.f, 0.f, 0.f};
        #pragma unroll
        for (int ks = 0; ks < 6; ++ks) {
            f16x8 afr = *(const f16x8*)&w2_s[((ct * 6 + ks) * 64 + lane) * 8];
            Y[ct] = __builtin_amdgcn_mfma_f32_16x16x32_f16(afr, bfr[ks], Y[ct], 0, 0, 0);
        }
    }
    #pragma unroll
    for (int ct = 0; ct < 8; ++ct) {
        int col = ct * 16 + kgrp * 4;
        float4 bv = *((const float4*)(b2f + col));
        uint2 xr = make_uint2(0u, 0u);
        if (valid) xr = *((const uint2*)(Xb + (size_t)node * 128 + col));
        __half2 x01 = *(__half2*)&xr.x, x23 = *(__half2*)&xr.y;
        Y[ct][0] += bv.x + __low2float(x01);
        Y[ct][1] += bv.y + __high2float(x01);
        Y[ct][2] += bv.z + __low2float(x23);
        Y[ct][3] += bv.w + __high2float(x23);
    }
    float s = 0.f;
    #pragma unroll
    for (int ct = 0; ct < 8; ++ct) s += Y[ct][0] + Y[ct][1] + Y[ct][2] + Y[ct][3];
    s += __shfl_xor(s, 16); s += __shfl_xor(s, 32);
    const float mu = s * (1.0f / 128.0f);
    float s2 = 0.f;
    #pragma unroll
    for (int ct = 0; ct < 8; ++ct)
        #pragma unroll
        for (int rr = 0; rr < 4; ++rr) { float d = Y[ct][rr] - mu; s2 = fmaf(d, d, s2); }
    s2 += __shfl_xor(s2, 16); s2 += __shfl_xor(s2, 32);
    const float rs = rsqrtf(s2 * (1.0f / 128.0f) + 1e-5f);
    if (valid) {
        #pragma unroll
        for (int ct = 0; ct < 8; ++ct) {
            int col = ct * 16 + kgrp * 4;
            float4 gg = *((const float4*)(g2 + col));
            float4 bb = *((const float4*)(b2ln + col));
            float4 o;
            o.x = (Y[ct][0] - mu) * rs * gg.x + bb.x;
            o.y = (Y[ct][1] - mu) * rs * gg.y + bb.y;
            o.z = (Y[ct][2] - mu) * rs * gg.z + bb.z;
            o.w = (Y[ct][3] - mu) * rs * gg.w + bb.w;
            *((float4*)(out + (size_t)node * 128 + col)) = o;
        }
    }
}

// ============ launch ============================================================
extern "C" void kernel_launch(void* const* d_in, const int* in_sizes, int n_in,
                              void* d_out, int out_size, void* d_ws, size_t ws_size,
                              hipStream_t stream)
{
    const float* feat = (const float*)d_in[0];
    const int*   knn  = (const int*)d_in[1];
    const float* dist = (const float*)d_in[2];
    const float* Wq   = (const float*)d_in[3];
    const float* Wk   = (const float*)d_in[4];
    const float* Wv   = (const float*)d_in[5];
    const float* Wo   = (const float*)d_in[6];
    const float* bo   = (const float*)d_in[7];
    const float* g1   = (const float*)d_in[8];
    const float* b1ln = (const float*)d_in[9];
    const float* W1   = (const float*)d_in[10];
    const float* b1f  = (const float*)d_in[11];
    const float* W2   = (const float*)d_in[12];
    const float* b2f  = (const float*)d_in[13];
    const float* g2   = (const float*)d_in[14];
    const float* b2ln = (const float*)d_in[15];
    float* out = (float*)d_out;

    const int n = in_sizes[0] / 128;
    const size_t ND = (size_t)n * 128;
    if (ws_size < 8 * ND + 262144) return;

    unsigned short* Qb   = (unsigned short*)d_ws;   // ND fp16
    unsigned short* Kb   = Qb + ND;                 // ND fp16
    unsigned short* Vb   = Kb + ND;                 // ND fp16
    unsigned short* attb = Vb + ND;                 // ND fp16
    unsigned short* Wsz  = attb + ND;               // 114688 fp16
    // buffers dead after k_attn get reused (row-disjoint kernels, stream-ordered):
    unsigned short* Xb   = Vb;                      // ND fp16 over dead V
    unsigned short* Hb   = Qb;                      // n*192 fp16 over dead Q+K

    k_prep <<<56, 256, 0, stream>>>(Wq, Wk, Wv, Wo, W1, W2, Wsz);
    k_qkv  <<<(n + 63) / 64,   256, 0, stream>>>(feat, Wsz, Qb, Kb, Vb, n);
    k_attn <<<(n + 3) / 4,     256, 0, stream>>>(Qb, Kb, Vb, knn, dist, attb, n);
    k_tail1<<<(n + 127) / 128, 512, 0, stream>>>(attb, feat, Wsz, bo, g1, b1ln, Xb, n);
    k_ffn1 <<<(n + 127) / 128, 512, 0, stream>>>(Xb, Wsz, b1f, Hb, n);
    k_ffn2 <<<(n + 127) / 128, 512, 0, stream>>>(Hb, Xb, Wsz, b2f, g2, b2ln, out, n);
}

// Round 6
// 179.850 us; speedup vs baseline: 24.2388x; 1.0620x over previous
//
#include <hip/hip_runtime.h>
#include <hip/hip_fp16.h>
#include <cmath>

typedef __attribute__((ext_vector_type(8))) _Float16 f16x8;
typedef __attribute__((ext_vector_type(4))) float f32x4;

__device__ __forceinline__ unsigned int pkh(float a, float b) {
    __half2 h = __floats2half2_rn(a, b);
    return *(unsigned int*)&h;
}
__device__ __forceinline__ float gelu_exact(float v) {
    return 0.5f * v * (1.0f + erff(v * 0.70710678118654752440f));
}
__device__ __forceinline__ __half2 shfl8h(__half2 x, int m) {
    int xi = *(int*)&x;
    int yi = __shfl_xor(xi, m, 8);
    return *(__half2*)&yi;
}

// ============ K0: weight prep — fp32 -> fp16, MFMA A-fragment order =============
// frag(ct,ks,l,j) = W[ks*32 + (l>>4)*8 + j][ct*16 + (l&15)]  (A-operand = W^T tile)
// shorts: Wq@0 Wk@16384 Wv@32768 Wo@49152 W1@65536 W2@90112 (total 114688)
__global__ __launch_bounds__(256, 1) void k_prep(
    const float* __restrict__ Wq, const float* __restrict__ Wk, const float* __restrict__ Wv,
    const float* __restrict__ Wo, const float* __restrict__ W1, const float* __restrict__ W2,
    unsigned short* __restrict__ wsz)
{
    int f = blockIdx.x * 256 + threadIdx.x;
    const float* W; unsigned short* dst; int M, KS, fl;
    if (f < 2048)       { W = Wq; dst = wsz;         M = 128; KS = 4; fl = f; }
    else if (f < 4096)  { W = Wk; dst = wsz + 16384; M = 128; KS = 4; fl = f - 2048; }
    else if (f < 6144)  { W = Wv; dst = wsz + 32768; M = 128; KS = 4; fl = f - 4096; }
    else if (f < 8192)  { W = Wo; dst = wsz + 49152; M = 128; KS = 4; fl = f - 6144; }
    else if (f < 11264) { W = W1; dst = wsz + 65536; M = 192; KS = 4; fl = f - 8192; }
    else if (f < 14336) { W = W2; dst = wsz + 90112; M = 128; KS = 6; fl = f - 11264; }
    else return;
    const int l  = fl & 63;
    const int ks = (fl >> 6) % KS;
    const int ct = (fl >> 6) / KS;
    const int k0 = ks * 32 + (l >> 4) * 8;
    const int col = ct * 16 + (l & 15);
    unsigned short tmp[8];
    #pragma unroll
    for (int j = 0; j < 8; ++j) {
        __half hh = __float2half(W[(size_t)(k0 + j) * M + col]);
        tmp[j] = *(unsigned short*)&hh;
    }
    ((uint4*)dst)[fl] = *(uint4*)tmp;
}

// ============ K1: QKV projection — frags from global; K|V interleaved out =======
__global__ __launch_bounds__(256, 4) void k_qkv(
    const float* __restrict__ feat, const unsigned short* __restrict__ wsz,
    unsigned short* __restrict__ Qb, unsigned short* __restrict__ KVb, int n)
{
    const int w = threadIdx.x >> 6, lane = threadIdx.x & 63;
    const int lrow = lane & 15, kgrp = lane >> 4;
    const int node = blockIdx.x * 64 + w * 16 + lrow;
    const bool valid = node < n;

    f16x8 bfr[4];
    #pragma unroll
    for (int ks = 0; ks < 4; ++ks) {
        float4 lo = make_float4(0.f, 0.f, 0.f, 0.f), hi = lo;
        if (valid) {
            const float* p = feat + (size_t)node * 128 + ks * 32 + kgrp * 8;
            lo = *(const float4*)p;
            hi = *(const float4*)(p + 4);
        }
        f16x8 b;
        b[0] = (_Float16)lo.x; b[1] = (_Float16)lo.y; b[2] = (_Float16)lo.z; b[3] = (_Float16)lo.w;
        b[4] = (_Float16)hi.x; b[5] = (_Float16)hi.y; b[6] = (_Float16)hi.z; b[7] = (_Float16)hi.w;
        bfr[ks] = b;
    }

    for (int mat = 0; mat < 3; ++mat) {
        const unsigned short* wb = wsz + mat * 16384;
        f32x4 acc[8];
        #pragma unroll
        for (int ct = 0; ct < 8; ++ct) acc[ct] = (f32x4){0.f, 0.f, 0.f, 0.f};
        #pragma unroll
        for (int ct = 0; ct < 8; ++ct)
            #pragma unroll
            for (int ks = 0; ks < 4; ++ks) {
                f16x8 afr = *(const f16x8*)(wb + ((size_t)(ct * 4 + ks) * 64 + lane) * 8);
                acc[ct] = __builtin_amdgcn_mfma_f32_16x16x32_f16(afr, bfr[ks], acc[ct], 0, 0, 0);
            }
        if (valid) {
            unsigned short* O = (mat == 0) ? (Qb + (size_t)node * 128)
                              : (KVb + (size_t)node * 256 + (mat == 2 ? 128 : 0));
            #pragma unroll
            for (int ct = 0; ct < 8; ++ct) {
                int col = ct * 16 + kgrp * 4;
                *((uint2*)(O + col)) =
                    make_uint2(pkh(acc[ct][0], acc[ct][1]), pkh(acc[ct][2], acc[ct][3]));
            }
        }
    }
}

// ============ K2: KNN attention — interleaved K|V gather; frag-order output =====
__global__ __launch_bounds__(256, 4) void k_attn(
    const unsigned short* __restrict__ Qb, const unsigned short* __restrict__ KVb,
    const int* __restrict__ knn, const float* __restrict__ dist,
    unsigned short* __restrict__ attf, int n)
{
    const int lane = threadIdx.x & 63;
    const int node = blockIdx.x * 4 + (threadIdx.x >> 6);
    if (node >= n) return;
    const int h = lane >> 3, r = lane & 7;
    const float hs = exp2f(-(float)(h + 1));

    int idx[4]; float sd[4];
    #pragma unroll
    for (int jj = 0; jj < 4; ++jj) {
        int j = r + jj * 8;
        idx[jj] = knn[(size_t)node * 32 + j];
        sd[jj]  = dist[(size_t)node * 32 + j] * hs;
    }

    const unsigned short* qp = Qb + (size_t)node * 128 + h * 16;
    __half2 q2[8];
    *((uint4*)&q2[0]) = *(const uint4*)qp;
    *((uint4*)&q2[4]) = *(const uint4*)(qp + 8);

    uint4 k0[4], k1[4], v0[4], v1[4];
    #pragma unroll
    for (int jj = 0; jj < 4; ++jj) {
        const unsigned short* kvp = KVb + (size_t)idx[jj] * 256 + h * 16;
        k0[jj] = *(const uint4*)kvp;
        k1[jj] = *(const uint4*)(kvp + 8);
        v0[jj] = *(const uint4*)(kvp + 128);
        v1[jj] = *(const uint4*)(kvp + 136);
    }

    float ap[4], an[4];
    #pragma unroll
    for (int jj = 0; jj < 4; ++jj) {
        const __half2* ka = (const __half2*)&k0[jj];
        const __half2* kb = (const __half2*)&k1[jj];
        __half2 s0 = __hmul2(q2[0], ka[0]);
        s0 = __hfma2(q2[1], ka[1], s0);
        s0 = __hfma2(q2[2], ka[2], s0);
        s0 = __hfma2(q2[3], ka[3], s0);
        __half2 s1 = __hmul2(q2[4], kb[0]);
        s1 = __hfma2(q2[5], kb[1], s1);
        s1 = __hfma2(q2[6], kb[2], s1);
        s1 = __hfma2(q2[7], kb[3], s1);
        float s = __low2float(s0) + __high2float(s0) + __low2float(s1) + __high2float(s1);
        float raw = s * 0.25f;
        ap[jj] = raw - sd[jj];
        an[jj] = (-raw - sd[jj]) * (1.0f / 0.6f);
    }

    float mp = fmaxf(fmaxf(ap[0], ap[1]), fmaxf(ap[2], ap[3]));
    float mn = fmaxf(fmaxf(an[0], an[1]), fmaxf(an[2], an[3]));
    #pragma unroll
    for (int msk = 1; msk < 8; msk <<= 1) {
        mp = fmaxf(mp, __shfl_xor(mp, msk, 8));
        mn = fmaxf(mn, __shfl_xor(mn, msk, 8));
    }
    float ep[4], en[4], sp = 0.f, sn = 0.f;
    #pragma unroll
    for (int jj = 0; jj < 4; ++jj) {
        ep[jj] = expf(ap[jj] - mp); sp += ep[jj];
        en[jj] = expf(an[jj] - mn); sn += en[jj];
    }
    #pragma unroll
    for (int msk = 1; msk < 8; msk <<= 1) {
        sp += __shfl_xor(sp, msk, 8);
        sn += __shfl_xor(sn, msk, 8);
    }
    const float isp = 1.0f / sp;
    const float isn = 1.5f / sn;

    __half2 acc2[8];
    #pragma unroll
    for (int i = 0; i < 8; ++i) acc2[i] = __float2half2_rn(0.f);
    #pragma unroll
    for (int jj = 0; jj < 4; ++jj) {
        float wgt = ep[jj] * isp - en[jj] * isn;
        __half2 w2 = __float2half2_rn(wgt);
        const __half2* va = (const __half2*)&v0[jj];
        const __half2* vb = (const __half2*)&v1[jj];
        acc2[0] = __hfma2(w2, va[0], acc2[0]);
        acc2[1] = __hfma2(w2, va[1], acc2[1]);
        acc2[2] = __hfma2(w2, va[2], acc2[2]);
        acc2[3] = __hfma2(w2, va[3], acc2[3]);
        acc2[4] = __hfma2(w2, vb[0], acc2[4]);
        acc2[5] = __hfma2(w2, vb[1], acc2[5]);
        acc2[6] = __hfma2(w2, vb[2], acc2[6]);
        acc2[7] = __hfma2(w2, vb[3], acc2[7]);
    }
    #pragma unroll
    for (int i = 0; i < 8; ++i) {
        acc2[i] = __hadd2(acc2[i], shfl8h(acc2[i], 1));
        acc2[i] = __hadd2(acc2[i], shfl8h(acc2[i], 2));
        acc2[i] = __hadd2(acc2[i], shfl8h(acc2[i], 4));
    }
    if (r == 0) {
        // fragment-order store: k = h*16+i -> ks=h>>1, kg=(h&1)*2 + (i>>3), j=i&7
        const int g = node >> 4, lrow = node & 15;
        unsigned short* op = attf + (size_t)g * 2048 + (h >> 1) * 512 + (h & 1) * 256 + lrow * 8;
        *((uint4*)op)         = *(uint4*)&acc2[0];
        *((uint4*)(op + 128)) = *(uint4*)&acc2[4];
    }
}

// ============ K3: fused tail — X=LN1(att@Wo+bo+feat); H=gelu(X@W1+b1);
//              out=LN2(H@W2+b2+X). 64 rows/block; weights from global (L2-hot);
//              X/H transposed through 24KB LDS; X residual in packed-fp16 regs. ==
__global__ __launch_bounds__(256, 4) void k_tail(
    const unsigned short* __restrict__ attf, const float* __restrict__ feat,
    const unsigned short* __restrict__ wsz,
    const float* __restrict__ bo, const float* __restrict__ g1, const float* __restrict__ b1ln,
    const float* __restrict__ b1f, const float* __restrict__ b2f,
    const float* __restrict__ g2, const float* __restrict__ b2ln,
    float* __restrict__ out, int n)
{
    __shared__ __align__(16) unsigned short hls[12288];   // 24 KB: X frags then H frags
    const int tid = threadIdx.x;
    const int w = tid >> 6, lane = tid & 63;
    const int lrow = lane & 15, kgrp = lane >> 4;
    const int node = blockIdx.x * 64 + w * 16 + lrow;
    const bool valid = node < n;
    const int g = blockIdx.x * 4 + w;

    // ---- GEMM1: X = att @ Wo + bo + feat ----
    f16x8 bfr[6];
    #pragma unroll
    for (int ks = 0; ks < 4; ++ks) {
        uint4 u = make_uint4(0u, 0u, 0u, 0u);
        if (valid) u = *(const uint4*)(attf + (size_t)g * 2048 + ks * 512 + kgrp * 128 + lrow * 8);
        bfr[ks] = *(f16x8*)&u;
    }
    const unsigned short* wo = wsz + 49152;
    f32x4 X[8];
    #pragma unroll
    for (int ct = 0; ct < 8; ++ct) {
        X[ct] = (f32x4){0.f, 0.f, 0.f, 0.f};
        #pragma unroll
        for (int ks = 0; ks < 4; ++ks) {
            f16x8 afr = *(const f16x8*)(wo + ((size_t)(ct * 4 + ks) * 64 + lane) * 8);
            X[ct] = __builtin_amdgcn_mfma_f32_16x16x32_f16(afr, bfr[ks], X[ct], 0, 0, 0);
        }
    }
    #pragma unroll
    for (int ct = 0; ct < 8; ++ct) {
        int col = ct * 16 + kgrp * 4;
        float4 bv = *((const float4*)(bo + col));
        float4 fr = make_float4(0.f, 0.f, 0.f, 0.f);
        if (valid) fr = *((const float4*)(feat + (size_t)node * 128 + col));
        X[ct][0] += bv.x + fr.x; X[ct][1] += bv.y + fr.y;
        X[ct][2] += bv.z + fr.z; X[ct][3] += bv.w + fr.w;
    }
    // LN1 (node's 128 values live in lanes {lrow, lrow^16, lrow^32, lrow^48})
    float s = 0.f;
    #pragma unroll
    for (int ct = 0; ct < 8; ++ct) s += X[ct][0] + X[ct][1] + X[ct][2] + X[ct][3];
    s += __shfl_xor(s, 16); s += __shfl_xor(s, 32);
    const float mu1 = s * (1.0f / 128.0f);
    float s2 = 0.f;
    #pragma unroll
    for (int ct = 0; ct < 8; ++ct)
        #pragma unroll
        for (int rr = 0; rr < 4; ++rr) { float d = X[ct][rr] - mu1; s2 = fmaf(d, d, s2); }
    s2 += __shfl_xor(s2, 16); s2 += __shfl_xor(s2, 32);
    const float rs1 = rsqrtf(s2 * (1.0f / 128.0f) + 1e-5f);

    uint2 xnh[8];                                          // packed fp16 LN1 output
    #pragma unroll
    for (int ct = 0; ct < 8; ++ct) {
        int col = ct * 16 + kgrp * 4;
        float4 gg = *((const float4*)(g1 + col));
        float4 bb = *((const float4*)(b1ln + col));
        float x0 = (X[ct][0] - mu1) * rs1 * gg.x + bb.x;
        float x1 = (X[ct][1] - mu1) * rs1 * gg.y + bb.y;
        float x2 = (X[ct][2] - mu1) * rs1 * gg.z + bb.z;
        float x3 = (X[ct][3] - mu1) * rs1 * gg.w + bb.w;
        xnh[ct] = make_uint2(pkh(x0, x1), pkh(x2, x3));
        int ks = col >> 5, kg = (col & 31) >> 3, jb = col & 7;
        *((uint2*)&hls[((w * 4 + ks) * 4 + kg) * 128 + lrow * 8 + jb]) = xnh[ct];
    }
    __syncthreads();
    #pragma unroll
    for (int ks = 0; ks < 4; ++ks)
        bfr[ks] = *(const f16x8*)&hls[((w * 4 + ks) * 4 + kgrp) * 128 + lrow * 8];
    __syncthreads();                                       // all X reads done before H writes

    // ---- GEMM2: H = gelu(X@W1 + b1) -> LDS frags (acc transient per ct) ----
    const unsigned short* w1 = wsz + 65536;
    #pragma unroll
    for (int ct = 0; ct < 12; ++ct) {
        f32x4 acc = (f32x4){0.f, 0.f, 0.f, 0.f};
        #pragma unroll
        for (int ks = 0; ks < 4; ++ks) {
            f16x8 afr = *(const f16x8*)(w1 + ((size_t)(ct * 4 + ks) * 64 + lane) * 8);
            acc = __builtin_amdgcn_mfma_f32_16x16x32_f16(afr, bfr[ks], acc, 0, 0, 0);
        }
        int col = ct * 16 + kgrp * 4;
        float4 bv = *((const float4*)(b1f + col));
        float h0 = gelu_exact(acc[0] + bv.x);
        float h1 = gelu_exact(acc[1] + bv.y);
        float h2 = gelu_exact(acc[2] + bv.z);
        float h3 = gelu_exact(acc[3] + bv.w);
        int ks = col >> 5, kg = (col & 31) >> 3, jb = col & 7;
        *((uint2*)&hls[((w * 6 + ks) * 4 + kg) * 128 + lrow * 8 + jb]) =
            make_uint2(pkh(h0, h1), pkh(h2, h3));
    }
    __syncthreads();
    #pragma unroll
    for (int ks = 0; ks < 6; ++ks)
        bfr[ks] = *(const f16x8*)&hls[((w * 6 + ks) * 4 + kgrp) * 128 + lrow * 8];

    // ---- GEMM3: Y = H@W2 + b2 + X; LN2 ----
    const unsigned short* w2 = wsz + 90112;
    f32x4 Y[8];
    #pragma unroll
    for (int ct = 0; ct < 8; ++ct) {
        Y[ct] = (f32x4){0.f, 0.f, 0.f, 0.f};
        #pragma unroll
        for (int ks = 0; ks < 6; ++ks) {
            f16x8 afr = *(const f16x8*)(w2 + ((size_t)(ct * 6 + ks) * 64 + lane) * 8);
            Y[ct] = __builtin_amdgcn_mfma_f32_16x16x32_f16(afr, bfr[ks], Y[ct], 0, 0, 0);
        }
    }
    #pragma unroll
    for (int ct = 0; ct < 8; ++ct) {
        int col = ct * 16 + kgrp * 4;
        float4 bv = *((const float4*)(b2f + col));
        __half2 x01 = *(__half2*)&xnh[ct].x, x23 = *(__half2*)&xnh[ct].y;
        Y[ct][0] += bv.x + __low2float(x01);
        Y[ct][1] += bv.y + __high2float(x01);
        Y[ct][2] += bv.z + __low2float(x23);
        Y[ct][3] += bv.w + __high2float(x23);
    }
    float t1 = 0.f;
    #pragma unroll
    for (int ct = 0; ct < 8; ++ct) t1 += Y[ct][0] + Y[ct][1] + Y[ct][2] + Y[ct][3];
    t1 += __shfl_xor(t1, 16); t1 += __shfl_xor(t1, 32);
    const float mu2 = t1 * (1.0f / 128.0f);
    float t2 = 0.f;
    #pragma unroll
    for (int ct = 0; ct < 8; ++ct)
        #pragma unroll
        for (int rr = 0; rr < 4; ++rr) { float d = Y[ct][rr] - mu2; t2 = fmaf(d, d, t2); }
    t2 += __shfl_xor(t2, 16); t2 += __shfl_xor(t2, 32);
    const float rs2 = rsqrtf(t2 * (1.0f / 128.0f) + 1e-5f);
    if (valid) {
        #pragma unroll
        for (int ct = 0; ct < 8; ++ct) {
            int col = ct * 16 + kgrp * 4;
            float4 gg = *((const float4*)(g2 + col));
            float4 bb = *((const float4*)(b2ln + col));
            float4 o;
            o.x = (Y[ct][0] - mu2) * rs2 * gg.x + bb.x;
            o.y = (Y[ct][1] - mu2) * rs2 * gg.y + bb.y;
            o.z = (Y[ct][2] - mu2) * rs2 * gg.z + bb.z;
            o.w = (Y[ct][3] - mu2) * rs2 * gg.w + bb.w;
            *((float4*)(out + (size_t)node * 128 + col)) = o;
        }
    }
}

// ============ launch ============================================================
extern "C" void kernel_launch(void* const* d_in, const int* in_sizes, int n_in,
                              void* d_out, int out_size, void* d_ws, size_t ws_size,
                              hipStream_t stream)
{
    const float* feat = (const float*)d_in[0];
    const int*   knn  = (const int*)d_in[1];
    const float* dist = (const float*)d_in[2];
    const float* Wq   = (const float*)d_in[3];
    const float* Wk   = (const float*)d_in[4];
    const float* Wv   = (const float*)d_in[5];
    const float* Wo   = (const float*)d_in[6];
    const float* bo   = (const float*)d_in[7];
    const float* g1   = (const float*)d_in[8];
    const float* b1ln = (const float*)d_in[9];
    const float* W1   = (const float*)d_in[10];
    const float* b1f  = (const float*)d_in[11];
    const float* W2   = (const float*)d_in[12];
    const float* b2f  = (const float*)d_in[13];
    const float* g2   = (const float*)d_in[14];
    const float* b2ln = (const float*)d_in[15];
    float* out = (float*)d_out;

    const int n = in_sizes[0] / 128;
    const size_t ND = (size_t)n * 128;
    if (ws_size < 8 * ND + 262144) return;

    unsigned short* Qb   = (unsigned short*)d_ws;   // ND fp16
    unsigned short* KVb  = Qb + ND;                 // 2*ND fp16, K|V interleaved per node
    unsigned short* attf = KVb + 2 * ND;            // ND fp16, fragment order
    unsigned short* Wsz  = attf + ND;               // 114688 fp16

    k_prep<<<56, 256, 0, stream>>>(Wq, Wk, Wv, Wo, W1, W2, Wsz);
    k_qkv <<<(n + 63) / 64, 256, 0, stream>>>(feat, Wsz, Qb, KVb, n);
    k_attn<<<(n + 3) / 4,   256, 0, stream>>>(Qb, KVb, knn, dist, attf, n);
    k_tail<<<(n + 63) / 64, 256, 0, stream>>>(attf, feat, Wsz, bo, g1, b1ln, b1f, b2f,
                                              g2, b2ln, out, n);
}